// Round 4
// baseline (273.338 us; speedup 1.0000x reference)
//
#include <hip/hip_runtime.h>
#include <hip/hip_bf16.h>
#include <math.h>

#define B_      16
#define L_      2048
#define D_MODEL 320
#define D_INNER 640
#define D_STATE 16
#define DT_RANK 20
#define H_OUT   128
#define VOCAB   65
#define N_TIS   30
#define TT      8    // t-tile in xdbl producer
#define ST      64   // t-tile in fallback fused scan
#define NCHUNK  16   // fallback scan chunks (128 t each)
#define CHLEN   (L_/NCHUNK)
#define NCH2    32   // new scan chunks (64 t each)
#define CHL2    (L_/NCH2)

// workspace layout (floats)
static constexpr size_t OFF_MSEQ  = 0;                            // 65*1280
static constexpr size_t OFF_MTIS  = OFF_MSEQ  + VOCAB*1280;       // 30*1280
static constexpr size_t OFF_YSCAN = OFF_MTIS  + N_TIS*1280;       // 16*640
static constexpr size_t OFF_CLAST = OFF_YSCAN + B_*D_INNER;       // 16*16
static constexpr size_t OFF_FLAG  = OFF_CLAST + B_*16;            // 16 slots (flag at [0])
static constexpr size_t OFF_XD20  = OFF_FLAG  + 16;               // B*L*20 (dt rows)
static constexpr size_t OFF_BBAR  = OFF_XD20 + (size_t)B_*L_*20;  // B*16*L ([b][s][t], fallback)
static constexpr size_t OFF_BT    = OFF_BBAR + (size_t)B_*D_STATE*L_; // B*L*16 ([b][t][s], new)
static constexpr size_t OFF_PC    = OFF_BT   + (size_t)B_*L_*D_STATE; // fallback P
static constexpr size_t OFF_SC    = OFF_PC   + (size_t)B_*NCHUNK*40*256;
static constexpr size_t OFF_PCN   = OFF_SC   + (size_t)B_*NCHUNK*40*256; // new: Es per (b,c,d)
static constexpr size_t OFF_SCN   = OFF_PCN  + (size_t)B_*NCH2*D_INNER;  // new: h[16] per (b,c,d)

__device__ __forceinline__ float fast_rcp(float x) { return __builtin_amdgcn_rcpf(x); }
__device__ __forceinline__ float silu_f(float x) { return x * fast_rcp(1.0f + __expf(-x)); }

// ---------- K0: verify A_log == log(arange(1,17)) broadcast over d; write flag ----------
__global__ __launch_bounds__(256) void k_check(const float* __restrict__ A_log,
                                               float* __restrict__ ws)
{
    __shared__ int oksh;
    int tid = threadIdx.x;
    if (tid == 0) oksh = 1;
    __syncthreads();
    int ok = 1;
    for (int i = tid; i < D_INNER*D_STATE; i += 256) {
        int s = i & 15;
        float v = A_log[i];
        if (v != A_log[s]) ok = 0;               // rows must be identical over d
        if (i < 16) {
            float a = __expf(v);                 // -A_s must be ~ (s+1)
            if (fabsf(a - (float)(s+1)) > 1e-3f*(float)(s+1)) ok = 0;
        }
    }
    if (!ok) atomicAnd(&oksh, 0);
    __syncthreads();
    if (tid == 0) ((int*)ws)[OFF_FLAG] = oksh;
}

// ---------- A0+A1 fused: renorm embedding row (max_norm=2) then M-row = row @ inW-slice^T ----------
__global__ __launch_bounds__(256) void k_mbuild(
    const float* __restrict__ seqW, const float* __restrict__ tisW,
    const float* __restrict__ inW, float* __restrict__ ws)
{
    __shared__ float a_l[256];
    __shared__ float red[4];
    int v = blockIdx.x, tid = threadIdx.x;
    int K, wofs; const float* src; float* dstM;
    if (v < VOCAB) { K = 256; wofs = 0;   src = seqW + (size_t)v*256;        dstM = ws + OFF_MSEQ + (size_t)v*1280; }
    else           { K = 64;  wofs = 256; src = tisW + (size_t)(v-VOCAB)*64; dstM = ws + OFF_MTIS + (size_t)(v-VOCAB)*1280; }
    float x = (tid < K) ? src[tid] : 0.0f;
    float ss = x * x;
    #pragma unroll
    for (int o = 32; o; o >>= 1) ss += __shfl_xor(ss, o);
    if ((tid & 63) == 0) red[tid >> 6] = ss;
    __syncthreads();
    float tot = red[0] + red[1] + red[2] + red[3];
    float scale = fminf(1.0f, 2.0f / fmaxf(sqrtf(tot), 1e-12f));
    a_l[tid] = (tid < K) ? x * scale : 0.0f;
    __syncthreads();

    int wv = tid >> 6, l = tid & 63;
    float4 a4 = ((const float4*)a_l)[l];
    int j0 = blockIdx.y * 256 + wv * 64;
    bool lane_on = (4*l < K);
    for (int jj = 0; jj < 64; jj += 4) {
        float p[4];
        #pragma unroll
        for (int u = 0; u < 4; ++u) {
            float pv = 0.0f;
            if (lane_on) {
                const float4 w4 = *(const float4*)(inW + (size_t)(j0 + jj + u)*320 + wofs + 4*l);
                pv = a4.x*w4.x + a4.y*w4.y + a4.z*w4.z + a4.w*w4.w;
            }
            p[u] = pv;
        }
        float ta, tb;
        ta=__shfl_xor(p[0],1); tb=__shfl_xor(p[1],1); p[0]=(l&1)?(p[1]+tb):(p[0]+ta);
        ta=__shfl_xor(p[2],1); tb=__shfl_xor(p[3],1); p[2]=(l&1)?(p[3]+tb):(p[2]+ta);
        ta=__shfl_xor(p[0],2); tb=__shfl_xor(p[2],2); p[0]=(l&2)?(p[2]+tb):(p[0]+ta);
        p[0]+=__shfl_xor(p[0],4);  p[0]+=__shfl_xor(p[0],8);
        p[0]+=__shfl_xor(p[0],16); p[0]+=__shfl_xor(p[0],32);
        if (l < 4) dstM[j0 + jj + l] = p[0];
    }
}

// ---------- K2: conv+silu -> x_proj rows 0..35 -> XD20 + BBAR + BT; C at t_last ----------
__global__ __launch_bounds__(256) void k_xdbl(
    const int* __restrict__ idx, const int* __restrict__ tissue_id,
    const int* __restrict__ seq_lengths,
    const float* __restrict__ conv_w, const float* __restrict__ conv_b,
    const float* __restrict__ xW, float* __restrict__ ws)
{
    __shared__ float u_l[TT*641];
    __shared__ float xd_l[TT*36];
    __shared__ int   idx_l[TT+3];
    int b = blockIdx.y;
    int t0 = blockIdx.x * TT;
    int t_last = seq_lengths[b] - 1;
    if (t0 > t_last) return;
    int tid = threadIdx.x;
    const float* Mseq = ws + OFF_MSEQ;
    const float* Mtis = ws + OFF_MTIS;
    int tis = tissue_id[b];
    if (tid < TT+3) {
        int t = t0 - 3 + tid;
        idx_l[tid] = (t >= 0) ? idx[b*L_ + t] : 0;
    }
    __syncthreads();

    for (int d = tid; d < D_INNER; d += 256) {
        float w0 = conv_w[d*4+0], w1 = conv_w[d*4+1], w2 = conv_w[d*4+2], w3 = conv_w[d*4+3];
        float cb = conv_b[d];
        float mt = Mtis[(size_t)tis*1280 + d];
        float xzv[TT+3];
        #pragma unroll
        for (int k = 0; k < TT+3; ++k) {
            unsigned ro = (unsigned)idx_l[k] * 1280u;
            xzv[k] = ro ? (Mseq[ro + (unsigned)d] + mt) : 0.0f;
        }
        #pragma unroll
        for (int t = 0; t < TT; ++t) {
            float c = cb;
            c = fmaf(w0, xzv[t+0], c);
            c = fmaf(w1, xzv[t+1], c);
            c = fmaf(w2, xzv[t+2], c);
            c = fmaf(w3, xzv[t+3], c);
            u_l[t*641 + d] = silu_f(c);
        }
    }
    __syncthreads();

    {
        int w = tid >> 6, l = tid & 63;
        float wreg[9][10];
        #pragma unroll
        for (int kk = 0; kk < 9; ++kk) {
            const float* xr = xW + (size_t)(w + 4*kk)*D_INNER + l;
            #pragma unroll
            for (int i = 0; i < 10; ++i) wreg[kk][i] = xr[64*i];
        }
        for (int t = 0; t < TT; ++t) {
            float p[9];
            #pragma unroll
            for (int kk = 0; kk < 9; ++kk) p[kk] = 0.f;
            #pragma unroll
            for (int i = 0; i < 10; ++i) {
                float ui = u_l[t*641 + l + 64*i];
                #pragma unroll
                for (int kk = 0; kk < 9; ++kk) p[kk] = fmaf(wreg[kk][i], ui, p[kk]);
            }
            // merge-tree reduce: 9 partial-registers -> 1 (lane l<9 holds output l)
            {
                float ta, tb;
                ta=__shfl_xor(p[0],1); tb=__shfl_xor(p[1],1); p[0]=(l&1)?(p[1]+tb):(p[0]+ta);
                ta=__shfl_xor(p[2],1); tb=__shfl_xor(p[3],1); p[2]=(l&1)?(p[3]+tb):(p[2]+ta);
                ta=__shfl_xor(p[4],1); tb=__shfl_xor(p[5],1); p[4]=(l&1)?(p[5]+tb):(p[4]+ta);
                ta=__shfl_xor(p[6],1); tb=__shfl_xor(p[7],1); p[6]=(l&1)?(p[7]+tb):(p[6]+ta);
                p[8]+=__shfl_xor(p[8],1);
                ta=__shfl_xor(p[0],2); tb=__shfl_xor(p[2],2); p[0]=(l&2)?(p[2]+tb):(p[0]+ta);
                ta=__shfl_xor(p[4],2); tb=__shfl_xor(p[6],2); p[4]=(l&2)?(p[6]+tb):(p[4]+ta);
                p[8]+=__shfl_xor(p[8],2);
                ta=__shfl_xor(p[0],4); tb=__shfl_xor(p[4],4); p[0]=(l&4)?(p[4]+tb):(p[0]+ta);
                p[8]+=__shfl_xor(p[8],4);
                ta=__shfl_xor(p[0],8); tb=__shfl_xor(p[8],8); p[0]=(l&8)?(p[8]+tb):(p[0]+ta);
                p[0]+=__shfl_xor(p[0],16);
                p[0]+=__shfl_xor(p[0],32);
            }
            if (l < 9) xd_l[t*36 + w + 4*l] = p[0];
        }
        if (t_last < t0 + TT) {
            int tl = t_last - t0;
            float pc[4];
            #pragma unroll
            for (int k = 0; k < 4; ++k) pc[k] = 0.f;
            #pragma unroll
            for (int i = 0; i < 10; ++i) {
                float ui = u_l[tl*641 + l + 64*i];
                #pragma unroll
                for (int k = 0; k < 4; ++k)
                    pc[k] = fmaf(xW[(size_t)(36 + w + 4*k)*D_INNER + l + 64*i], ui, pc[k]);
            }
            #pragma unroll
            for (int o = 32; o; o >>= 1) {
                #pragma unroll
                for (int k = 0; k < 4; ++k) pc[k] += __shfl_xor(pc[k], o);
            }
            if (l == 0) {
                #pragma unroll
                for (int k = 0; k < 4; ++k) ws[OFF_CLAST + b*16 + w + 4*k] = pc[k];
            }
        }
    }
    __syncthreads();

    {
        int nt = min(TT, t_last - t0 + 1);
        int cnt = nt * 20;
        float* dst = ws + OFF_XD20 + ((size_t)b*L_ + t0)*20;
        for (int o = tid; o < cnt; o += 256) {
            int t = o / 20, r = o - t*20;
            dst[o] = xd_l[t*36 + r];
        }
        int cntB = nt * 16;
        if (tid < cntB) {
            int s, tt;
            if (nt == TT) { s = tid >> 3; tt = tid & 7; }
            else          { s = tid / nt; tt = tid - s*nt; }
            ws[OFF_BBAR + ((size_t)b*D_STATE + s)*L_ + t0 + tt] = xd_l[tt*36 + 20 + s];
        }
        // transposed copy BT[b][t][s] for the power-scan (s contiguous)
        for (int o = tid; o < cntB; o += 256) {
            int t = o >> 4, s = o & 15;
            ws[OFF_BT + ((size_t)b*L_ + t0 + t)*16 + s] = xd_l[t*36 + 20 + s];
        }
    }
}

// ---------- K3n: power-form scan (requires A_s = -(s+1); flag-gated) ----------
// d-per-lane; backward t within 64-t chunk; ONE exp2 per (d,t): W_s = E^(s+1).
// h_c[s] = sum_t exp(A_s*r_t)*du_t*B_s(t), r_t = suffix-sum of delta. No LDS, no barriers.
__global__ __launch_bounds__(128) void k_scan2(
    const int* __restrict__ idx, const int* __restrict__ tissue_id,
    const int* __restrict__ seq_lengths,
    const float* __restrict__ conv_w, const float* __restrict__ conv_b,
    const float* __restrict__ dtW, const float* __restrict__ dtb,
    float* __restrict__ ws)
{
    if (((const int*)ws)[OFF_FLAG] == 0) return;
    int b = blockIdx.y, c = blockIdx.z;
    int t_last = seq_lengths[b] - 1;
    int t_begin = c * CHL2;
    if (t_begin > t_last) return;
    int t_end = min(t_begin + CHL2 - 1, t_last);
    int d = blockIdx.x * 128 + threadIdx.x;         // 5*128 = 640
    unsigned du = (unsigned)d;
    int tis = tissue_id[b];
    const float* Mseq = ws + OFF_MSEQ;
    const float* xd   = ws + OFF_XD20 + (size_t)b*L_*20;
    const float* BT   = ws + OFF_BT   + (size_t)b*L_*16;
    const int*   idxb = idx + b*L_;

    float dtw_r[20];
    #pragma unroll
    for (int i = 0; i < 20; i += 4) {
        float4 w4 = *(const float4*)(dtW + d*20 + i);
        dtw_r[i] = w4.x; dtw_r[i+1] = w4.y; dtw_r[i+2] = w4.z; dtw_r[i+3] = w4.w;
    }
    float4 cw4 = *(const float4*)(conv_w + d*4);
    float  cb  = conv_b[d];
    float  dtb_v = dtb[d];
    float  mt  = ws[OFF_MTIS + (size_t)tis*1280 + d];
    const float L2E = 1.44269504089f;

    // conv window: xw[3]=x(t), xw[0]=x(t-3)
    float xw0, xw1, xw2, xw3;
    {
        int t;
        t = t_end;     { int row = idxb[t]; xw3 = row ? (Mseq[(unsigned)row*1280u + du] + mt) : 0.f; }
        t = t_end - 1; { float v = 0.f; if (t >= 0) { int row = idxb[t]; v = row ? (Mseq[(unsigned)row*1280u + du] + mt) : 0.f; } xw2 = v; }
        t = t_end - 2; { float v = 0.f; if (t >= 0) { int row = idxb[t]; v = row ? (Mseq[(unsigned)row*1280u + du] + mt) : 0.f; } xw1 = v; }
        t = t_end - 3; { float v = 0.f; if (t >= 0) { int row = idxb[t]; v = row ? (Mseq[(unsigned)row*1280u + du] + mt) : 0.f; } xw0 = v; }
    }

    float h[16];
    #pragma unroll
    for (int s = 0; s < 16; ++s) h[s] = 0.f;
    float r = 0.f;

    for (int t = t_end; t >= t_begin; --t) {
        // u = silu(conv)
        float cc = cb;
        cc = fmaf(cw4.x, xw0, cc);
        cc = fmaf(cw4.y, xw1, cc);
        cc = fmaf(cw4.z, xw2, cc);
        cc = fmaf(cw4.w, xw3, cc);
        float u = silu_f(cc);
        // delta = softplus(dt-dot)
        const float4* xr4 = (const float4*)(xd + (size_t)t*20);
        float x = dtb_v;
        #pragma unroll
        for (int q = 0; q < 5; ++q) {
            float4 x4 = xr4[q];
            x = fmaf(x4.x, dtw_r[4*q+0], x);
            x = fmaf(x4.y, dtw_r[4*q+1], x);
            x = fmaf(x4.z, dtw_r[4*q+2], x);
            x = fmaf(x4.w, dtw_r[4*q+3], x);
        }
        float e  = __expf(-fabsf(x));
        float dl = fmaxf(x, 0.0f) + __logf(1.0f + e);
        float F  = dl * u;
        // E = exp(-r); powers E^1..E^16 (tree, all exponents <= 0: underflow-safe)
        float p1 = exp2f(-L2E * r);
        float p2 = p1*p1, p3 = p2*p1, p4 = p2*p2;
        float p5 = p4*p1, p6 = p4*p2, p7 = p4*p3, p8 = p4*p4;
        float p9 = p8*p1, p10 = p8*p2, p11 = p8*p3, p12 = p8*p4;
        float p13 = p8*p5, p14 = p8*p6, p15 = p8*p7, p16 = p8*p8;
        const float4* Bt4 = (const float4*)(BT + (size_t)t*16);
        float4 B0 = Bt4[0], B1 = Bt4[1], B2 = Bt4[2], B3 = Bt4[3];
        h[0]  = fmaf(F*B0.x, p1,  h[0]);
        h[1]  = fmaf(F*B0.y, p2,  h[1]);
        h[2]  = fmaf(F*B0.z, p3,  h[2]);
        h[3]  = fmaf(F*B0.w, p4,  h[3]);
        h[4]  = fmaf(F*B1.x, p5,  h[4]);
        h[5]  = fmaf(F*B1.y, p6,  h[5]);
        h[6]  = fmaf(F*B1.z, p7,  h[6]);
        h[7]  = fmaf(F*B1.w, p8,  h[7]);
        h[8]  = fmaf(F*B2.x, p9,  h[8]);
        h[9]  = fmaf(F*B2.y, p10, h[9]);
        h[10] = fmaf(F*B2.z, p11, h[10]);
        h[11] = fmaf(F*B2.w, p12, h[11]);
        h[12] = fmaf(F*B3.x, p13, h[12]);
        h[13] = fmaf(F*B3.y, p14, h[13]);
        h[14] = fmaf(F*B3.z, p15, h[14]);
        h[15] = fmaf(F*B3.w, p16, h[15]);
        // advance suffix-sum and conv window
        r += dl;
        xw3 = xw2; xw2 = xw1; xw1 = xw0;
        {
            int tn = t - 4;
            float v = 0.f;
            if (tn >= 0) { int row = idxb[tn]; v = row ? (Mseq[(unsigned)row*1280u + du] + mt) : 0.f; }
            xw0 = v;
        }
    }

    // chunk transfer: Es (P_s = Es^(s+1) reconstructed in k_comb) + h[16]
    ws[OFF_PCN + ((size_t)b*NCH2 + c)*D_INNER + d] = exp2f(-L2E * r);
    float* dst = ws + OFF_SCN + (((size_t)b*NCH2 + c)*D_INNER + d)*16;
    ((float4*)dst)[0] = make_float4(h[0],  h[1],  h[2],  h[3]);
    ((float4*)dst)[1] = make_float4(h[4],  h[5],  h[6],  h[7]);
    ((float4*)dst)[2] = make_float4(h[8],  h[9],  h[10], h[11]);
    ((float4*)dst)[3] = make_float4(h[12], h[13], h[14], h[15]);
}

// ---------- K3: fallback chunk-parallel fused scan (general A; flag==0 only) ----------
__global__ __launch_bounds__(256) void k_scanc(
    const int* __restrict__ idx, const int* __restrict__ tissue_id,
    const int* __restrict__ seq_lengths,
    const float* __restrict__ conv_w, const float* __restrict__ conv_b,
    const float* __restrict__ dtW, const float* __restrict__ dtb,
    const float* __restrict__ A_log, float* __restrict__ ws)
{
    if (((const int*)ws)[OFF_FLAG] != 0) return;
    __shared__ float xd_t[ST*20];
    __shared__ float dl_t[16*68];
    __shared__ float du_t[16*68];
    __shared__ float Bb_t[16*68];
    __shared__ float sdred[16*17];
    __shared__ int   idx_t[ST+3];

    int dg = blockIdx.x, b = blockIdx.y, c = blockIdx.z;
    int t_last = seq_lengths[b] - 1;
    int t_begin = c * CHLEN;
    if (t_begin > t_last) return;
    int t_end = min(t_begin + CHLEN - 1, t_last);
    int tid = threadIdx.x;
    int dl = tid >> 4, s = tid & 15;
    int dd = tid & 15, tg = tid >> 4;
    int d_own = dg*16 + dd;
    unsigned dco = (unsigned)d_own;
    int tis = tissue_id[b];
    const float* Mseq = ws + OFF_MSEQ;

    float dtw_r[20];
    #pragma unroll
    for (int i = 0; i < 20; i += 4) {
        float4 w4 = *(const float4*)(dtW + d_own*20 + i);
        dtw_r[i] = w4.x; dtw_r[i+1] = w4.y; dtw_r[i+2] = w4.z; dtw_r[i+3] = w4.w;
    }
    float4 cw4 = *(const float4*)(conv_w + d_own*4);
    float  cb  = conv_b[d_own];
    float  dtb_v = dtb[d_own];
    float  mt  = ws[OFF_MTIS + (size_t)tis*1280 + d_own];
    float As = -__expf(A_log[(dg*16 + dl)*D_STATE + s]) * 1.44269504089f;

    float h = 0.0f;
    float sdp = 0.0f;
    for (int t0 = t_begin; t0 <= t_end; t0 += ST) {
        int nt = min(ST, t_end - t0 + 1);
        if (tid < ST+3) {
            int t = t0 - 3 + tid;
            idx_t[tid] = (t >= 0 && t < L_) ? idx[b*L_ + t] : 0;
        }
        {
            const float4* src = (const float4*)(ws + OFF_XD20 + ((size_t)b*L_ + t0)*20);
            float4* dst = (float4*)xd_t;
            int cnt4 = nt * 5;
            for (int o = tid; o < cnt4; o += 256) dst[o] = src[o];
        }
        {
            int lr = tid >> 4, c4 = (tid & 15) * 4;
            if (c4 < nt)
                *(float4*)(Bb_t + lr*68 + c4) =
                    *(const float4*)(ws + OFF_BBAR + ((size_t)b*D_STATE + lr)*L_ + t0 + c4);
        }
        __syncthreads();

        {
            int ttb = tg * 4;
            if (ttb < nt) {
                float xz[7];
                #pragma unroll
                for (int k = 0; k < 7; ++k) {
                    unsigned ro = (unsigned)idx_t[ttb + k] * 1280u;
                    xz[k] = ro ? (Mseq[ro + dco] + mt) : 0.0f;
                }
                float dl4[4], du4[4];
                bool full = (ttb + 3 < nt);
                #pragma unroll
                for (int j = 0; j < 4; ++j) {
                    int tt = ttb + j;
                    if (full || tt < nt) {
                        float cc = cb;
                        cc = fmaf(cw4.x, xz[j+0], cc);
                        cc = fmaf(cw4.y, xz[j+1], cc);
                        cc = fmaf(cw4.z, xz[j+2], cc);
                        cc = fmaf(cw4.w, xz[j+3], cc);
                        float u = silu_f(cc);
                        const float* xr = xd_t + tt*20;
                        float x = dtb_v;
                        #pragma unroll
                        for (int rr = 0; rr < 20; rr += 4) {
                            float4 x4 = *(const float4*)(xr + rr);
                            x = fmaf(x4.x, dtw_r[rr+0], x);
                            x = fmaf(x4.y, dtw_r[rr+1], x);
                            x = fmaf(x4.z, dtw_r[rr+2], x);
                            x = fmaf(x4.w, dtw_r[rr+3], x);
                        }
                        float e = __expf(-fabsf(x));
                        float sp = fmaxf(x, 0.0f) + __logf(1.0f + e);
                        dl4[j] = sp;
                        du4[j] = sp * u;
                        sdp += sp;
                    } else { dl4[j] = 0.f; du4[j] = 0.f; }
                }
                if (full) {
                    *(float4*)(dl_t + dd*68 + ttb) = make_float4(dl4[0], dl4[1], dl4[2], dl4[3]);
                    *(float4*)(du_t + dd*68 + ttb) = make_float4(du4[0], du4[1], du4[2], du4[3]);
                } else {
                    for (int j = 0; j < 4 && ttb + j < nt; ++j) {
                        dl_t[dd*68 + ttb + j] = dl4[j];
                        du_t[dd*68 + ttb + j] = du4[j];
                    }
                }
            }
        }
        __syncthreads();

        {
            int q4 = nt >> 2;
            #pragma unroll 8
            for (int q = 0; q < q4; ++q) {
                float4 d4 = *(const float4*)(dl_t + dl*68 + 4*q);
                float4 u4 = *(const float4*)(du_t + dl*68 + 4*q);
                float4 b4 = *(const float4*)(Bb_t + s*68 + 4*q);
                float e0 = exp2f(d4.x*As), e1 = exp2f(d4.y*As);
                float e2 = exp2f(d4.z*As), e3 = exp2f(d4.w*As);
                float c0 = u4.x*b4.x, c1 = u4.y*b4.y;
                float c2 = u4.z*b4.z, c3 = u4.w*b4.w;
                h = fmaf(e0, h, c0); h = fmaf(e1, h, c1);
                h = fmaf(e2, h, c2); h = fmaf(e3, h, c3);
            }
            for (int tt = q4*4; tt < nt; ++tt) {
                float dlt = dl_t[dl*68 + tt];
                h = fmaf(exp2f(dlt * As), h, du_t[dl*68 + tt] * Bb_t[s*68 + tt]);
            }
        }
        __syncthreads();
    }
    sdred[tg*17 + dd] = sdp;
    __syncthreads();
    float sd = 0.0f;
    #pragma unroll
    for (int g = 0; g < 16; ++g) sd += sdred[g*17 + dl];
    float P = exp2f(As * sd);
    size_t base = (((size_t)b*NCHUNK + c)*40 + dg)*256 + tid;
    ws[OFF_PC + base] = P;
    ws[OFF_SC + base] = h;
}

// ---------- K3b: combine chunk transfers, apply C_last, reduce over s ----------
__global__ __launch_bounds__(256) void k_comb(const int* __restrict__ seq_lengths,
                                              float* __restrict__ ws)
{
    int b = blockIdx.y, dg = blockIdx.x;
    int tid = threadIdx.x;
    int dl = tid >> 4, s = tid & 15;
    int t_last = seq_lengths[b] - 1;
    int flag = ((const int*)ws)[OFF_FLAG];
    float h = 0.0f;
    if (flag) {
        int d = dg*16 + dl;
        int n = s + 1;
        int ncv = t_last / CHL2 + 1;
        for (int c = 0; c < ncv; ++c) {
            float Es = ws[OFF_PCN + ((size_t)b*NCH2 + c)*D_INNER + d];
            float e2 = Es*Es, e4 = e2*e2, e8 = e4*e4, e16 = e8*e8;
            float W = (n & 1) ? Es : 1.0f;
            W *= (n & 2)  ? e2  : 1.0f;
            W *= (n & 4)  ? e4  : 1.0f;
            W *= (n & 8)  ? e8  : 1.0f;
            W *= (n & 16) ? e16 : 1.0f;
            float Sc = ws[OFF_SCN + (((size_t)b*NCH2 + c)*D_INNER + d)*16 + s];
            h = fmaf(W, h, Sc);
        }
    } else {
        int ncv = t_last / CHLEN + 1;
        for (int c = 0; c < ncv; ++c) {
            size_t base = (((size_t)b*NCHUNK + c)*40 + dg)*256 + tid;
            h = fmaf(ws[OFF_PC + base], h, ws[OFF_SC + base]);
        }
    }
    float v = h * ws[OFF_CLAST + b*16 + s];
    v += __shfl_xor(v, 1); v += __shfl_xor(v, 2);
    v += __shfl_xor(v, 4); v += __shfl_xor(v, 8);
    if (s == 0) ws[OFF_YSCAN + (size_t)b*D_INNER + dg*16 + dl] = v;
}

// ---------- K5: per-batch epilogue, 1024 threads: parallel dots ----------
__global__ __launch_bounds__(1024) void k_final(
    const int* __restrict__ idx, const int* __restrict__ tissue_id,
    const int* __restrict__ seq_lengths,
    const float* __restrict__ conv_w, const float* __restrict__ conv_b,
    const float* __restrict__ Dskip, const float* __restrict__ outW,
    const float* __restrict__ p1W, const float* __restrict__ p1b,
    const float* __restrict__ p2W, const float* __restrict__ p2b,
    const float* __restrict__ ws, float* __restrict__ out)
{
    __shared__ float y_l[D_INNER];
    __shared__ float o_l[D_MODEL];
    __shared__ float h1_l[H_OUT];
    int b = blockIdx.x, tid = threadIdx.x;
    int t_last = seq_lengths[b] - 1;
    int tis = tissue_id[b];
    const float* Mseq = ws + OFF_MSEQ;
    const float* Mtis = ws + OFF_MTIS;
    int rows[4];
    #pragma unroll
    for (int k = 0; k < 4; ++k) {
        int t = t_last - 3 + k;
        rows[k] = (t >= 0) ? idx[b*L_ + t] : 0;
    }
    if (tid < D_INNER) {
        int d = tid;
        float conv = conv_b[d];
        const float* cw = conv_w + d*4;
        #pragma unroll
        for (int k = 0; k < 4; ++k) {
            unsigned ro = (unsigned)rows[k] * 1280u;
            float xzv = ro ? (Mseq[ro + (unsigned)d] + Mtis[(size_t)tis*1280 + d]) : 0.0f;
            conv += cw[k] * xzv;
        }
        float u = silu_f(conv);
        unsigned roL = (unsigned)rows[3] * 1280u;
        float z = roL ? (Mseq[roL + 640u + (unsigned)d] + Mtis[(size_t)tis*1280 + 640 + d]) : 0.0f;
        float ys = ws[OFF_YSCAN + (size_t)b*D_INNER + d];
        y_l[d] = (ys + u * Dskip[d]) * silu_f(z);
    }
    __syncthreads();
    {
        int j = tid >> 1, half = tid & 1;
        float acc = 0.f;
        if (j < D_MODEL) {
            const float* w = outW + (size_t)j*D_INNER + half*320;
            const float* y = y_l + half*320;
            #pragma unroll 4
            for (int k = 0; k < 320; k += 4) {
                float4 w4 = *(const float4*)(w + k);
                acc += y[k]*w4.x + y[k+1]*w4.y + y[k+2]*w4.z + y[k+3]*w4.w;
            }
        }
        acc += __shfl_xor(acc, 1);
        if (j < D_MODEL && half == 0) o_l[j] = acc;
    }
    __syncthreads();
    {
        int j = tid >> 3, part = tid & 7;
        float acc = 0.f;
        if (j < H_OUT) {
            const float* w = p1W + (size_t)j*D_MODEL + part*40;
            const float* o = o_l + part*40;
            #pragma unroll
            for (int k = 0; k < 40; k += 4) {
                float4 w4 = *(const float4*)(w + k);
                acc += o[k]*w4.x + o[k+1]*w4.y + o[k+2]*w4.z + o[k+3]*w4.w;
            }
        }
        acc += __shfl_xor(acc, 1); acc += __shfl_xor(acc, 2); acc += __shfl_xor(acc, 4);
        if (j < H_OUT && part == 0) h1_l[j] = fmaxf(acc + p1b[j], 0.0f);
    }
    __syncthreads();
    if (tid < 64) {
        float v = h1_l[tid]*p2W[tid] + h1_l[tid+64]*p2W[tid+64];
        v += __shfl_xor(v, 32); v += __shfl_xor(v, 16); v += __shfl_xor(v, 8);
        v += __shfl_xor(v, 4);  v += __shfl_xor(v, 2);  v += __shfl_xor(v, 1);
        if (tid == 0) out[b] = v + p2b[0];
    }
}

extern "C" void kernel_launch(void* const* d_in, const int* in_sizes, int n_in,
                              void* d_out, int out_size, void* d_ws, size_t ws_size,
                              hipStream_t stream)
{
    const int*   idx   = (const int*)d_in[0];
    const int*   tis   = (const int*)d_in[1];
    const int*   slen  = (const int*)d_in[2];
    const float* seqW  = (const float*)d_in[3];
    const float* tisW  = (const float*)d_in[4];
    const float* inW   = (const float*)d_in[5];
    const float* convw = (const float*)d_in[6];
    const float* convb = (const float*)d_in[7];
    const float* xW    = (const float*)d_in[8];
    const float* dtW   = (const float*)d_in[9];
    const float* dtb   = (const float*)d_in[10];
    const float* Alog  = (const float*)d_in[11];
    const float* Dsk   = (const float*)d_in[12];
    const float* outW  = (const float*)d_in[13];
    const float* p1W   = (const float*)d_in[14];
    const float* p1b   = (const float*)d_in[15];
    const float* p2W   = (const float*)d_in[16];
    const float* p2b   = (const float*)d_in[17];
    float* ws  = (float*)d_ws;
    float* out = (float*)d_out;

    hipLaunchKernelGGL(k_check,  dim3(1),               dim3(256), 0, stream, Alog, ws);
    hipLaunchKernelGGL(k_mbuild, dim3(VOCAB + N_TIS, 5), dim3(256), 0, stream, seqW, tisW, inW, ws);
    hipLaunchKernelGGL(k_xdbl,   dim3(L_/TT, B_),        dim3(256), 0, stream,
                       idx, tis, slen, convw, convb, xW, ws);
    hipLaunchKernelGGL(k_scan2,  dim3(D_INNER/128, B_, NCH2), dim3(128), 0, stream,
                       idx, tis, slen, convw, convb, dtW, dtb, ws);
    hipLaunchKernelGGL(k_scanc,  dim3(D_INNER/16, B_, NCHUNK), dim3(256), 0, stream,
                       idx, tis, slen, convw, convb, dtW, dtb, Alog, ws);
    hipLaunchKernelGGL(k_comb,   dim3(D_INNER/16, B_),   dim3(256), 0, stream, slen, ws);
    hipLaunchKernelGGL(k_final,  dim3(B_),               dim3(1024), 0, stream,
                       idx, tis, slen, convw, convb, Dsk, outW, p1W, p1b, p2W, p2b, ws, out);
}

// Round 5
// 250.719 us; speedup vs baseline: 1.0902x; 1.0902x over previous
//
#include <hip/hip_runtime.h>
#include <hip/hip_bf16.h>
#include <math.h>

#define B_      16
#define L_      2048
#define D_MODEL 320
#define D_INNER 640
#define D_STATE 16
#define DT_RANK 20
#define H_OUT   128
#define VOCAB   65
#define N_TIS   30
#define TT      8    // t-tile in xdbl producer
#define ST      64   // t-tile in fallback fused scan
#define NCHUNK  16   // fallback scan chunks (128 t each)
#define CHLEN   (L_/NCHUNK)
#define NCH2    64   // power-scan chunks (32 t each)
#define CHL2    (L_/NCH2)

// workspace layout (floats) — total 12,452,880 floats = 49.8 MB (<= proven round-4 footprint)
static constexpr size_t OFF_MSEQ  = 0;                              // 65*1280
static constexpr size_t OFF_MTIS  = OFF_MSEQ  + VOCAB*1280;         // 30*1280
static constexpr size_t OFF_YSCAN = OFF_MTIS  + N_TIS*1280;         // 16*640
static constexpr size_t OFF_CLAST = OFF_YSCAN + B_*D_INNER;         // 16*16
static constexpr size_t OFF_FLAG  = OFF_CLAST + B_*16;              // 16 slots
static constexpr size_t OFF_XDB   = OFF_FLAG  + 16;                 // B*L*36: [b][t][0..19]=dt rows, [20..35]=B rows
static constexpr size_t OFF_PCN   = OFF_XDB  + (size_t)B_*L_*36;    // B*NCH2*640: Es per (b,c,d)
static constexpr size_t OFF_SCN   = OFF_PCN  + (size_t)B_*NCH2*D_INNER; // B*NCH2*640*16: h[16]
// fallback (flag==0) transfer arrays ALIAS the SCN region (mutually exclusive with power path)
static constexpr size_t OFF_PC    = OFF_SCN;
static constexpr size_t OFF_SC    = OFF_SCN + (size_t)B_*NCHUNK*40*256;

__device__ __forceinline__ float fast_rcp(float x) { return __builtin_amdgcn_rcpf(x); }
__device__ __forceinline__ float silu_f(float x) { return x * fast_rcp(1.0f + __expf(-x)); }

// ---------- A0+A1 fused: renorm embedding rows -> M = row @ inW^T; last x-block runs A-structure check ----------
__global__ __launch_bounds__(256) void k_mbuild(
    const float* __restrict__ seqW, const float* __restrict__ tisW,
    const float* __restrict__ inW, const float* __restrict__ A_log,
    float* __restrict__ ws)
{
    int v = blockIdx.x, tid = threadIdx.x;
    if (v == VOCAB + N_TIS) {               // fused k_check (one block)
        if (blockIdx.y != 0) return;
        __shared__ int oksh;
        if (tid == 0) oksh = 1;
        __syncthreads();
        int ok = 1;
        for (int i = tid; i < D_INNER*D_STATE; i += 256) {
            int s = i & 15;
            float val = A_log[i];
            if (val != A_log[s]) ok = 0;                 // rows identical over d
            if (i < 16) {
                float a = __expf(val);                   // -A_s ~ (s+1)
                if (fabsf(a - (float)(s+1)) > 1e-3f*(float)(s+1)) ok = 0;
            }
        }
        if (!ok) atomicAnd(&oksh, 0);
        __syncthreads();
        if (tid == 0) ((int*)ws)[OFF_FLAG] = oksh;
        return;
    }

    __shared__ float a_l[256];
    __shared__ float red[4];
    int K, wofs; const float* src; float* dstM;
    if (v < VOCAB) { K = 256; wofs = 0;   src = seqW + (size_t)v*256;        dstM = ws + OFF_MSEQ + (size_t)v*1280; }
    else           { K = 64;  wofs = 256; src = tisW + (size_t)(v-VOCAB)*64; dstM = ws + OFF_MTIS + (size_t)(v-VOCAB)*1280; }
    float x = (tid < K) ? src[tid] : 0.0f;
    float ss = x * x;
    #pragma unroll
    for (int o = 32; o; o >>= 1) ss += __shfl_xor(ss, o);
    if ((tid & 63) == 0) red[tid >> 6] = ss;
    __syncthreads();
    float tot = red[0] + red[1] + red[2] + red[3];
    float scale = fminf(1.0f, 2.0f / fmaxf(sqrtf(tot), 1e-12f));
    a_l[tid] = (tid < K) ? x * scale : 0.0f;
    __syncthreads();

    int wv = tid >> 6, l = tid & 63;
    float4 a4 = ((const float4*)a_l)[l];
    int j0 = blockIdx.y * 256 + wv * 64;
    bool lane_on = (4*l < K);
    for (int jj = 0; jj < 64; jj += 4) {
        float p[4];
        #pragma unroll
        for (int u = 0; u < 4; ++u) {
            float pv = 0.0f;
            if (lane_on) {
                const float4 w4 = *(const float4*)(inW + (size_t)(j0 + jj + u)*320 + wofs + 4*l);
                pv = a4.x*w4.x + a4.y*w4.y + a4.z*w4.z + a4.w*w4.w;
            }
            p[u] = pv;
        }
        float ta, tb;
        ta=__shfl_xor(p[0],1); tb=__shfl_xor(p[1],1); p[0]=(l&1)?(p[1]+tb):(p[0]+ta);
        ta=__shfl_xor(p[2],1); tb=__shfl_xor(p[3],1); p[2]=(l&1)?(p[3]+tb):(p[2]+ta);
        ta=__shfl_xor(p[0],2); tb=__shfl_xor(p[2],2); p[0]=(l&2)?(p[2]+tb):(p[0]+ta);
        p[0]+=__shfl_xor(p[0],4);  p[0]+=__shfl_xor(p[0],8);
        p[0]+=__shfl_xor(p[0],16); p[0]+=__shfl_xor(p[0],32);
        if (l < 4) dstM[j0 + jj + l] = p[0];
    }
}

// ---------- K2: conv+silu -> x_proj rows 0..35 -> XDB[b][t][36]; C at t_last ----------
__global__ __launch_bounds__(256) void k_xdbl(
    const int* __restrict__ idx, const int* __restrict__ tissue_id,
    const int* __restrict__ seq_lengths,
    const float* __restrict__ conv_w, const float* __restrict__ conv_b,
    const float* __restrict__ xW, float* __restrict__ ws)
{
    __shared__ float u_l[TT*641];
    __shared__ float xd_l[TT*36];
    __shared__ int   idx_l[TT+3];
    int b = blockIdx.y;
    int t0 = blockIdx.x * TT;
    int t_last = seq_lengths[b] - 1;
    if (t0 > t_last) return;
    int tid = threadIdx.x;
    const float* Mseq = ws + OFF_MSEQ;
    const float* Mtis = ws + OFF_MTIS;
    int tis = tissue_id[b];
    if (tid < TT+3) {
        int t = t0 - 3 + tid;
        idx_l[tid] = (t >= 0) ? idx[b*L_ + t] : 0;
    }
    __syncthreads();

    for (int d = tid; d < D_INNER; d += 256) {
        float w0 = conv_w[d*4+0], w1 = conv_w[d*4+1], w2 = conv_w[d*4+2], w3 = conv_w[d*4+3];
        float cb = conv_b[d];
        float mt = Mtis[(size_t)tis*1280 + d];
        float xzv[TT+3];
        #pragma unroll
        for (int k = 0; k < TT+3; ++k) {
            unsigned ro = (unsigned)idx_l[k] * 1280u;
            xzv[k] = ro ? (Mseq[ro + (unsigned)d] + mt) : 0.0f;
        }
        #pragma unroll
        for (int t = 0; t < TT; ++t) {
            float c = cb;
            c = fmaf(w0, xzv[t+0], c);
            c = fmaf(w1, xzv[t+1], c);
            c = fmaf(w2, xzv[t+2], c);
            c = fmaf(w3, xzv[t+3], c);
            u_l[t*641 + d] = silu_f(c);
        }
    }
    __syncthreads();

    {
        int w = tid >> 6, l = tid & 63;
        float wreg[9][10];
        #pragma unroll
        for (int kk = 0; kk < 9; ++kk) {
            const float* xr = xW + (size_t)(w + 4*kk)*D_INNER + l;
            #pragma unroll
            for (int i = 0; i < 10; ++i) wreg[kk][i] = xr[64*i];
        }
        for (int t = 0; t < TT; ++t) {
            float p[9];
            #pragma unroll
            for (int kk = 0; kk < 9; ++kk) p[kk] = 0.f;
            #pragma unroll
            for (int i = 0; i < 10; ++i) {
                float ui = u_l[t*641 + l + 64*i];
                #pragma unroll
                for (int kk = 0; kk < 9; ++kk) p[kk] = fmaf(wreg[kk][i], ui, p[kk]);
            }
            // merge-tree reduce: 9 partial-registers -> 1 (lane l<9 holds output l)
            {
                float ta, tb;
                ta=__shfl_xor(p[0],1); tb=__shfl_xor(p[1],1); p[0]=(l&1)?(p[1]+tb):(p[0]+ta);
                ta=__shfl_xor(p[2],1); tb=__shfl_xor(p[3],1); p[2]=(l&1)?(p[3]+tb):(p[2]+ta);
                ta=__shfl_xor(p[4],1); tb=__shfl_xor(p[5],1); p[4]=(l&1)?(p[5]+tb):(p[4]+ta);
                ta=__shfl_xor(p[6],1); tb=__shfl_xor(p[7],1); p[6]=(l&1)?(p[7]+tb):(p[6]+ta);
                p[8]+=__shfl_xor(p[8],1);
                ta=__shfl_xor(p[0],2); tb=__shfl_xor(p[2],2); p[0]=(l&2)?(p[2]+tb):(p[0]+ta);
                ta=__shfl_xor(p[4],2); tb=__shfl_xor(p[6],2); p[4]=(l&2)?(p[6]+tb):(p[4]+ta);
                p[8]+=__shfl_xor(p[8],2);
                ta=__shfl_xor(p[0],4); tb=__shfl_xor(p[4],4); p[0]=(l&4)?(p[4]+tb):(p[0]+ta);
                p[8]+=__shfl_xor(p[8],4);
                ta=__shfl_xor(p[0],8); tb=__shfl_xor(p[8],8); p[0]=(l&8)?(p[8]+tb):(p[0]+ta);
                p[0]+=__shfl_xor(p[0],16);
                p[0]+=__shfl_xor(p[0],32);
            }
            if (l < 9) xd_l[t*36 + w + 4*l] = p[0];
        }
        if (t_last < t0 + TT) {
            int tl = t_last - t0;
            float pc[4];
            #pragma unroll
            for (int k = 0; k < 4; ++k) pc[k] = 0.f;
            #pragma unroll
            for (int i = 0; i < 10; ++i) {
                float ui = u_l[tl*641 + l + 64*i];
                #pragma unroll
                for (int k = 0; k < 4; ++k)
                    pc[k] = fmaf(xW[(size_t)(36 + w + 4*k)*D_INNER + l + 64*i], ui, pc[k]);
            }
            #pragma unroll
            for (int o = 32; o; o >>= 1) {
                #pragma unroll
                for (int k = 0; k < 4; ++k) pc[k] += __shfl_xor(pc[k], o);
            }
            if (l == 0) {
                #pragma unroll
                for (int k = 0; k < 4; ++k) ws[OFF_CLAST + b*16 + w + 4*k] = pc[k];
            }
        }
    }
    __syncthreads();

    // write-out: single contiguous copy of the [t][36] tile
    {
        int nt = min(TT, t_last - t0 + 1);
        int cnt = nt * 36;
        float* dst = ws + OFF_XDB + ((size_t)b*L_ + t0)*36;
        for (int o = tid; o < cnt; o += 256) dst[o] = xd_l[o];
    }
}

// ---------- K3n: power-form scan (A_s = -(s+1); flag-gated), software-pipelined ----------
// d-per-lane; backward t in 32-t chunk; 1 exp2 per (d,t). 2-t unrolled: next-t dt rows +
// conv gather issued a full COMPUTE ahead; B rows issued at compute-top. No LDS/barriers.
__global__ __launch_bounds__(128) void k_scan2(
    const int* __restrict__ idx, const int* __restrict__ tissue_id,
    const int* __restrict__ seq_lengths,
    const float* __restrict__ conv_w, const float* __restrict__ conv_b,
    const float* __restrict__ dtW, const float* __restrict__ dtb,
    float* __restrict__ ws)
{
    if (((const int*)ws)[OFF_FLAG] == 0) return;
    int b = blockIdx.y, c = blockIdx.z;
    int t_last = seq_lengths[b] - 1;
    int t_begin = c * CHL2;
    if (t_begin > t_last) return;
    int t_end = min(t_begin + CHL2 - 1, t_last);
    int d = blockIdx.x * 128 + threadIdx.x;
    unsigned dof = (unsigned)d;
    int tis = tissue_id[b];
    const float* Mseq = ws + OFF_MSEQ;
    const float4* XB  = (const float4*)(ws + OFF_XDB) + (size_t)b*L_*9;  // 9 float4 per t
    const int* idxb = idx + b*L_;

    float dtw_r[20];
    #pragma unroll
    for (int i = 0; i < 20; i += 4) {
        float4 w4 = *(const float4*)(dtW + d*20 + i);
        dtw_r[i] = w4.x; dtw_r[i+1] = w4.y; dtw_r[i+2] = w4.z; dtw_r[i+3] = w4.w;
    }
    float4 cw4 = *(const float4*)(conv_w + d*4);
    float  cb  = conv_b[d];
    float  dtb_v = dtb[d];
    float  mt  = ws[OFF_MTIS + (size_t)tis*1280 + d];
    const float L2E = 1.44269504089f;

    auto gath = [&](int t) -> float {
        int row = (t >= 0) ? idxb[t] : 0;
        return row ? (Mseq[(unsigned)row*1280u + dof] + mt) : 0.0f;
    };

    // conv window for t_end: xw0 = x(t_end-3) ... xw3 = x(t_end)
    float xw3 = gath(t_end);
    float xw2 = gath(t_end-1);
    float xw1 = gath(t_end-2);
    float xw0 = gath(t_end-3);

    float h[16];
    #pragma unroll
    for (int s = 0; s < 16; ++s) h[s] = 0.f;
    float r = 0.f;

    float4 a0,a1,a2,a3,a4;  float ga;
    float4 e0_,e1_,e2_,e3_,e4_; float ge;

#define LOADDT(P0,P1,P2,P3,P4,G,tt) { \
    const float4* _p = XB + (size_t)(tt)*9; \
    P0=_p[0]; P1=_p[1]; P2=_p[2]; P3=_p[3]; P4=_p[4]; \
    G = gath((tt)-4); }

#define COMPUTE(P0,P1,P2,P3,P4,G,tt) { \
    const float4* _pb = XB + (size_t)(tt)*9 + 5; \
    float4 B0=_pb[0], B1=_pb[1], B2=_pb[2], B3=_pb[3]; \
    float cc = cb; \
    cc = fmaf(cw4.x, xw0, cc); cc = fmaf(cw4.y, xw1, cc); \
    cc = fmaf(cw4.z, xw2, cc); cc = fmaf(cw4.w, xw3, cc); \
    float uu = silu_f(cc); \
    float x = dtb_v; \
    x = fmaf(P0.x, dtw_r[0],  x); x = fmaf(P0.y, dtw_r[1],  x); \
    x = fmaf(P0.z, dtw_r[2],  x); x = fmaf(P0.w, dtw_r[3],  x); \
    x = fmaf(P1.x, dtw_r[4],  x); x = fmaf(P1.y, dtw_r[5],  x); \
    x = fmaf(P1.z, dtw_r[6],  x); x = fmaf(P1.w, dtw_r[7],  x); \
    x = fmaf(P2.x, dtw_r[8],  x); x = fmaf(P2.y, dtw_r[9],  x); \
    x = fmaf(P2.z, dtw_r[10], x); x = fmaf(P2.w, dtw_r[11], x); \
    x = fmaf(P3.x, dtw_r[12], x); x = fmaf(P3.y, dtw_r[13], x); \
    x = fmaf(P3.z, dtw_r[14], x); x = fmaf(P3.w, dtw_r[15], x); \
    x = fmaf(P4.x, dtw_r[16], x); x = fmaf(P4.y, dtw_r[17], x); \
    x = fmaf(P4.z, dtw_r[18], x); x = fmaf(P4.w, dtw_r[19], x); \
    float ee = __expf(-fabsf(x)); \
    float dl = fmaxf(x, 0.0f) + __logf(1.0f + ee); \
    float F  = dl * uu; \
    float p1 = exp2f(-L2E * r); \
    float p2 = p1*p1, p3 = p2*p1, p4 = p2*p2; \
    float p5 = p4*p1, p6 = p4*p2, p7 = p4*p3, p8 = p4*p4; \
    float p9 = p8*p1, p10 = p8*p2, p11 = p8*p3, p12 = p8*p4; \
    float p13 = p8*p5, p14 = p8*p6, p15 = p8*p7, p16 = p8*p8; \
    h[0]  = fmaf(F*B0.x, p1,  h[0]);  h[1]  = fmaf(F*B0.y, p2,  h[1]); \
    h[2]  = fmaf(F*B0.z, p3,  h[2]);  h[3]  = fmaf(F*B0.w, p4,  h[3]); \
    h[4]  = fmaf(F*B1.x, p5,  h[4]);  h[5]  = fmaf(F*B1.y, p6,  h[5]); \
    h[6]  = fmaf(F*B1.z, p7,  h[6]);  h[7]  = fmaf(F*B1.w, p8,  h[7]); \
    h[8]  = fmaf(F*B2.x, p9,  h[8]);  h[9]  = fmaf(F*B2.y, p10, h[9]); \
    h[10] = fmaf(F*B2.z, p11, h[10]); h[11] = fmaf(F*B2.w, p12, h[11]); \
    h[12] = fmaf(F*B3.x, p13, h[12]); h[13] = fmaf(F*B3.y, p14, h[13]); \
    h[14] = fmaf(F*B3.z, p15, h[14]); h[15] = fmaf(F*B3.w, p16, h[15]); \
    r += dl; \
    xw3 = xw2; xw2 = xw1; xw1 = xw0; xw0 = G; }

    int t = t_end;
    LOADDT(a0,a1,a2,a3,a4,ga, t);
    for (;;) {
        int tb = t - 1;
        bool hasB = (tb >= t_begin);
        if (hasB) LOADDT(e0_,e1_,e2_,e3_,e4_,ge, tb);
        COMPUTE(a0,a1,a2,a3,a4,ga, t);
        if (!hasB) break;
        int ta = t - 2;
        bool hasA = (ta >= t_begin);
        if (hasA) LOADDT(a0,a1,a2,a3,a4,ga, ta);
        COMPUTE(e0_,e1_,e2_,e3_,e4_,ge, tb);
        if (!hasA) break;
        t = ta;
    }
#undef LOADDT
#undef COMPUTE

    // chunk transfer: Es (P_s = Es^(s+1) reconstructed in k_comb) + h[16]
    ws[OFF_PCN + ((size_t)b*NCH2 + c)*D_INNER + d] = exp2f(-L2E * r);
    float* dst = ws + OFF_SCN + (((size_t)b*NCH2 + c)*D_INNER + d)*16;
    ((float4*)dst)[0] = make_float4(h[0],  h[1],  h[2],  h[3]);
    ((float4*)dst)[1] = make_float4(h[4],  h[5],  h[6],  h[7]);
    ((float4*)dst)[2] = make_float4(h[8],  h[9],  h[10], h[11]);
    ((float4*)dst)[3] = make_float4(h[12], h[13], h[14], h[15]);
}

// ---------- K3: fallback chunk-parallel fused scan (general A; flag==0 only) ----------
__global__ __launch_bounds__(256) void k_scanc(
    const int* __restrict__ idx, const int* __restrict__ tissue_id,
    const int* __restrict__ seq_lengths,
    const float* __restrict__ conv_w, const float* __restrict__ conv_b,
    const float* __restrict__ dtW, const float* __restrict__ dtb,
    const float* __restrict__ A_log, float* __restrict__ ws)
{
    if (((const int*)ws)[OFF_FLAG] != 0) return;
    __shared__ float xd_t[ST*20];
    __shared__ float dl_t[16*68];
    __shared__ float du_t[16*68];
    __shared__ float Bb_t[16*68];
    __shared__ float sdred[16*17];
    __shared__ int   idx_t[ST+3];

    int dg = blockIdx.x, b = blockIdx.y, c = blockIdx.z;
    int t_last = seq_lengths[b] - 1;
    int t_begin = c * CHLEN;
    if (t_begin > t_last) return;
    int t_end = min(t_begin + CHLEN - 1, t_last);
    int tid = threadIdx.x;
    int dl = tid >> 4, s = tid & 15;
    int dd = tid & 15, tg = tid >> 4;
    int d_own = dg*16 + dd;
    unsigned dco = (unsigned)d_own;
    int tis = tissue_id[b];
    const float* Mseq = ws + OFF_MSEQ;

    float dtw_r[20];
    #pragma unroll
    for (int i = 0; i < 20; i += 4) {
        float4 w4 = *(const float4*)(dtW + d_own*20 + i);
        dtw_r[i] = w4.x; dtw_r[i+1] = w4.y; dtw_r[i+2] = w4.z; dtw_r[i+3] = w4.w;
    }
    float4 cw4 = *(const float4*)(conv_w + d_own*4);
    float  cb  = conv_b[d_own];
    float  dtb_v = dtb[d_own];
    float  mt  = ws[OFF_MTIS + (size_t)tis*1280 + d_own];
    float As = -__expf(A_log[(dg*16 + dl)*D_STATE + s]) * 1.44269504089f;

    float h = 0.0f;
    float sdp = 0.0f;
    for (int t0 = t_begin; t0 <= t_end; t0 += ST) {
        int nt = min(ST, t_end - t0 + 1);
        if (tid < ST+3) {
            int t = t0 - 3 + tid;
            idx_t[tid] = (t >= 0 && t < L_) ? idx[b*L_ + t] : 0;
        }
        {   // stage dt rows from XDB (stride 9 float4, take first 5)
            int cnt = nt * 5;
            for (int o = tid; o < cnt; o += 256) {
                int t = o / 5, q = o - t*5;
                ((float4*)xd_t)[o] =
                    *((const float4*)(ws + OFF_XDB) + ((size_t)b*L_ + t0 + t)*9 + q);
            }
        }
        {   // stage B rows transposed to [s][t]
            int cnt = nt * 16;
            for (int o = tid; o < cnt; o += 256) {
                int t = o >> 4, sB = o & 15;
                Bb_t[sB*68 + t] = ws[OFF_XDB + ((size_t)b*L_ + t0 + t)*36 + 20 + sB];
            }
        }
        __syncthreads();

        {
            int ttb = tg * 4;
            if (ttb < nt) {
                float xz[7];
                #pragma unroll
                for (int k = 0; k < 7; ++k) {
                    unsigned ro = (unsigned)idx_t[ttb + k] * 1280u;
                    xz[k] = ro ? (Mseq[ro + dco] + mt) : 0.0f;
                }
                float dl4[4], du4[4];
                bool full = (ttb + 3 < nt);
                #pragma unroll
                for (int j = 0; j < 4; ++j) {
                    int tt = ttb + j;
                    if (full || tt < nt) {
                        float cc = cb;
                        cc = fmaf(cw4.x, xz[j+0], cc);
                        cc = fmaf(cw4.y, xz[j+1], cc);
                        cc = fmaf(cw4.z, xz[j+2], cc);
                        cc = fmaf(cw4.w, xz[j+3], cc);
                        float u = silu_f(cc);
                        const float* xr = xd_t + tt*20;
                        float x = dtb_v;
                        #pragma unroll
                        for (int rr = 0; rr < 20; rr += 4) {
                            float4 x4 = *(const float4*)(xr + rr);
                            x = fmaf(x4.x, dtw_r[rr+0], x);
                            x = fmaf(x4.y, dtw_r[rr+1], x);
                            x = fmaf(x4.z, dtw_r[rr+2], x);
                            x = fmaf(x4.w, dtw_r[rr+3], x);
                        }
                        float e = __expf(-fabsf(x));
                        float sp = fmaxf(x, 0.0f) + __logf(1.0f + e);
                        dl4[j] = sp;
                        du4[j] = sp * u;
                        sdp += sp;
                    } else { dl4[j] = 0.f; du4[j] = 0.f; }
                }
                if (full) {
                    *(float4*)(dl_t + dd*68 + ttb) = make_float4(dl4[0], dl4[1], dl4[2], dl4[3]);
                    *(float4*)(du_t + dd*68 + ttb) = make_float4(du4[0], du4[1], du4[2], du4[3]);
                } else {
                    for (int j = 0; j < 4 && ttb + j < nt; ++j) {
                        dl_t[dd*68 + ttb + j] = dl4[j];
                        du_t[dd*68 + ttb + j] = du4[j];
                    }
                }
            }
        }
        __syncthreads();

        {
            int q4 = nt >> 2;
            #pragma unroll 8
            for (int q = 0; q < q4; ++q) {
                float4 d4 = *(const float4*)(dl_t + dl*68 + 4*q);
                float4 u4 = *(const float4*)(du_t + dl*68 + 4*q);
                float4 b4 = *(const float4*)(Bb_t + s*68 + 4*q);
                float e0 = exp2f(d4.x*As), e1 = exp2f(d4.y*As);
                float e2 = exp2f(d4.z*As), e3 = exp2f(d4.w*As);
                float c0 = u4.x*b4.x, c1 = u4.y*b4.y;
                float c2 = u4.z*b4.z, c3 = u4.w*b4.w;
                h = fmaf(e0, h, c0); h = fmaf(e1, h, c1);
                h = fmaf(e2, h, c2); h = fmaf(e3, h, c3);
            }
            for (int tt = q4*4; tt < nt; ++tt) {
                float dlt = dl_t[dl*68 + tt];
                h = fmaf(exp2f(dlt * As), h, du_t[dl*68 + tt] * Bb_t[s*68 + tt]);
            }
        }
        __syncthreads();
    }
    sdred[tg*17 + dd] = sdp;
    __syncthreads();
    float sd = 0.0f;
    #pragma unroll
    for (int g = 0; g < 16; ++g) sd += sdred[g*17 + dl];
    float P = exp2f(As * sd);
    size_t base = (((size_t)b*NCHUNK + c)*40 + dg)*256 + tid;
    ws[OFF_PC + base] = P;
    ws[OFF_SC + base] = h;
}

// ---------- K3b: combine chunk transfers, apply C_last, reduce over s ----------
__global__ __launch_bounds__(256) void k_comb(const int* __restrict__ seq_lengths,
                                              float* __restrict__ ws)
{
    int b = blockIdx.y, dg = blockIdx.x;
    int tid = threadIdx.x;
    int dl = tid >> 4, s = tid & 15;
    int t_last = seq_lengths[b] - 1;
    int flag = ((const int*)ws)[OFF_FLAG];
    float h = 0.0f;
    if (flag) {
        int d = dg*16 + dl;
        int n = s + 1;
        int ncv = t_last / CHL2 + 1;
        for (int c = 0; c < ncv; ++c) {
            float Es = ws[OFF_PCN + ((size_t)b*NCH2 + c)*D_INNER + d];
            float e2 = Es*Es, e4 = e2*e2, e8 = e4*e4, e16 = e8*e8;
            float W = (n & 1) ? Es : 1.0f;
            W *= (n & 2)  ? e2  : 1.0f;
            W *= (n & 4)  ? e4  : 1.0f;
            W *= (n & 8)  ? e8  : 1.0f;
            W *= (n & 16) ? e16 : 1.0f;
            float Sc = ws[OFF_SCN + (((size_t)b*NCH2 + c)*D_INNER + d)*16 + s];
            h = fmaf(W, h, Sc);
        }
    } else {
        int ncv = t_last / CHLEN + 1;
        for (int c = 0; c < ncv; ++c) {
            size_t base = (((size_t)b*NCHUNK + c)*40 + dg)*256 + tid;
            h = fmaf(ws[OFF_PC + base], h, ws[OFF_SC + base]);
        }
    }
    float v = h * ws[OFF_CLAST + b*16 + s];
    v += __shfl_xor(v, 1); v += __shfl_xor(v, 2);
    v += __shfl_xor(v, 4); v += __shfl_xor(v, 8);
    if (s == 0) ws[OFF_YSCAN + (size_t)b*D_INNER + dg*16 + dl] = v;
}

// ---------- K5: per-batch epilogue, 1024 threads: parallel dots ----------
__global__ __launch_bounds__(1024) void k_final(
    const int* __restrict__ idx, const int* __restrict__ tissue_id,
    const int* __restrict__ seq_lengths,
    const float* __restrict__ conv_w, const float* __restrict__ conv_b,
    const float* __restrict__ Dskip, const float* __restrict__ outW,
    const float* __restrict__ p1W, const float* __restrict__ p1b,
    const float* __restrict__ p2W, const float* __restrict__ p2b,
    const float* __restrict__ ws, float* __restrict__ out)
{
    __shared__ float y_l[D_INNER];
    __shared__ float o_l[D_MODEL];
    __shared__ float h1_l[H_OUT];
    int b = blockIdx.x, tid = threadIdx.x;
    int t_last = seq_lengths[b] - 1;
    int tis = tissue_id[b];
    const float* Mseq = ws + OFF_MSEQ;
    const float* Mtis = ws + OFF_MTIS;
    int rows[4];
    #pragma unroll
    for (int k = 0; k < 4; ++k) {
        int t = t_last - 3 + k;
        rows[k] = (t >= 0) ? idx[b*L_ + t] : 0;
    }
    if (tid < D_INNER) {
        int d = tid;
        float conv = conv_b[d];
        const float* cw = conv_w + d*4;
        #pragma unroll
        for (int k = 0; k < 4; ++k) {
            unsigned ro = (unsigned)rows[k] * 1280u;
            float xzv = ro ? (Mseq[ro + (unsigned)d] + Mtis[(size_t)tis*1280 + d]) : 0.0f;
            conv += cw[k] * xzv;
        }
        float u = silu_f(conv);
        unsigned roL = (unsigned)rows[3] * 1280u;
        float z = roL ? (Mseq[roL + 640u + (unsigned)d] + Mtis[(size_t)tis*1280 + 640 + d]) : 0.0f;
        float ys = ws[OFF_YSCAN + (size_t)b*D_INNER + d];
        y_l[d] = (ys + u * Dskip[d]) * silu_f(z);
    }
    __syncthreads();
    {
        int j = tid >> 1, half = tid & 1;
        float acc = 0.f;
        if (j < D_MODEL) {
            const float* w = outW + (size_t)j*D_INNER + half*320;
            const float* y = y_l + half*320;
            #pragma unroll 4
            for (int k = 0; k < 320; k += 4) {
                float4 w4 = *(const float4*)(w + k);
                acc += y[k]*w4.x + y[k+1]*w4.y + y[k+2]*w4.z + y[k+3]*w4.w;
            }
        }
        acc += __shfl_xor(acc, 1);
        if (j < D_MODEL && half == 0) o_l[j] = acc;
    }
    __syncthreads();
    {
        int j = tid >> 3, part = tid & 7;
        float acc = 0.f;
        if (j < H_OUT) {
            const float* w = p1W + (size_t)j*D_MODEL + part*40;
            const float* o = o_l + part*40;
            #pragma unroll
            for (int k = 0; k < 40; k += 4) {
                float4 w4 = *(const float4*)(w + k);
                acc += o[k]*w4.x + o[k+1]*w4.y + o[k+2]*w4.z + o[k+3]*w4.w;
            }
        }
        acc += __shfl_xor(acc, 1); acc += __shfl_xor(acc, 2); acc += __shfl_xor(acc, 4);
        if (j < H_OUT && part == 0) h1_l[j] = fmaxf(acc + p1b[j], 0.0f);
    }
    __syncthreads();
    if (tid < 64) {
        float v = h1_l[tid]*p2W[tid] + h1_l[tid+64]*p2W[tid+64];
        v += __shfl_xor(v, 32); v += __shfl_xor(v, 16); v += __shfl_xor(v, 8);
        v += __shfl_xor(v, 4);  v += __shfl_xor(v, 2);  v += __shfl_xor(v, 1);
        if (tid == 0) out[b] = v + p2b[0];
    }
}

extern "C" void kernel_launch(void* const* d_in, const int* in_sizes, int n_in,
                              void* d_out, int out_size, void* d_ws, size_t ws_size,
                              hipStream_t stream)
{
    const int*   idx   = (const int*)d_in[0];
    const int*   tis   = (const int*)d_in[1];
    const int*   slen  = (const int*)d_in[2];
    const float* seqW  = (const float*)d_in[3];
    const float* tisW  = (const float*)d_in[4];
    const float* inW   = (const float*)d_in[5];
    const float* convw = (const float*)d_in[6];
    const float* convb = (const float*)d_in[7];
    const float* xW    = (const float*)d_in[8];
    const float* dtW   = (const float*)d_in[9];
    const float* dtb   = (const float*)d_in[10];
    const float* Alog  = (const float*)d_in[11];
    const float* Dsk   = (const float*)d_in[12];
    const float* outW  = (const float*)d_in[13];
    const float* p1W   = (const float*)d_in[14];
    const float* p1b   = (const float*)d_in[15];
    const float* p2W   = (const float*)d_in[16];
    const float* p2b   = (const float*)d_in[17];
    float* ws  = (float*)d_ws;
    float* out = (float*)d_out;

    hipLaunchKernelGGL(k_mbuild, dim3(VOCAB + N_TIS + 1, 5), dim3(256), 0, stream,
                       seqW, tisW, inW, Alog, ws);
    hipLaunchKernelGGL(k_xdbl,   dim3(L_/TT, B_),        dim3(256), 0, stream,
                       idx, tis, slen, convw, convb, xW, ws);
    hipLaunchKernelGGL(k_scan2,  dim3(D_INNER/128, B_, NCH2), dim3(128), 0, stream,
                       idx, tis, slen, convw, convb, dtW, dtb, ws);
    hipLaunchKernelGGL(k_scanc,  dim3(D_INNER/16, B_, NCHUNK), dim3(256), 0, stream,
                       idx, tis, slen, convw, convb, dtW, dtb, Alog, ws);
    hipLaunchKernelGGL(k_comb,   dim3(D_INNER/16, B_),   dim3(256), 0, stream, slen, ws);
    hipLaunchKernelGGL(k_final,  dim3(B_),               dim3(1024), 0, stream,
                       idx, tis, slen, convw, convb, Dsk, outW, p1W, p1b, p2W, p2b, ws, out);
}

// Round 6
// 239.770 us; speedup vs baseline: 1.1400x; 1.0457x over previous
//
#include <hip/hip_runtime.h>
#include <hip/hip_bf16.h>
#include <math.h>

#define B_      16
#define L_      2048
#define D_MODEL 320
#define D_INNER 640
#define D_STATE 16
#define DT_RANK 20
#define H_OUT   128
#define VOCAB   65
#define N_TIS   30
#define TT      8    // t-tile in xdbl producer
#define ST      64   // t-tile in fallback fused scan
#define NCHUNK  16   // fallback scan chunks (128 t each)
#define CHLEN   (L_/NCHUNK)
#define NCH2    64   // power-scan chunks (32 t each)
#define CHL2    (L_/NCH2)

// workspace layout (floats) — total ~49.8 MB (<= proven footprint)
static constexpr size_t OFF_MSEQ  = 0;                              // 65*1280
static constexpr size_t OFF_MTIS  = OFF_MSEQ  + VOCAB*1280;         // 30*1280
static constexpr size_t OFF_YSCAN = OFF_MTIS  + N_TIS*1280;         // 16*640
static constexpr size_t OFF_CLAST = OFF_YSCAN + B_*D_INNER;         // 16*16
static constexpr size_t OFF_FLAG  = OFF_CLAST + B_*16;              // 16 slots
static constexpr size_t OFF_XDB   = OFF_FLAG  + 16;                 // B*L*36: [b][t][0..19]=dt rows, [20..35]=B rows
static constexpr size_t OFF_PCN   = OFF_XDB  + (size_t)B_*L_*36;    // B*NCH2*640: Es per (b,c,d)
static constexpr size_t OFF_SCN   = OFF_PCN  + (size_t)B_*NCH2*D_INNER; // B*NCH2*640*16: h[16]
// fallback (flag==0) transfer arrays ALIAS the SCN region (mutually exclusive with power path)
static constexpr size_t OFF_PC    = OFF_SCN;
static constexpr size_t OFF_SC    = OFF_SCN + (size_t)B_*NCHUNK*40*256;

__device__ __forceinline__ float fast_rcp(float x) { return __builtin_amdgcn_rcpf(x); }
__device__ __forceinline__ float silu_f(float x) { return x * fast_rcp(1.0f + __expf(-x)); }

// ---------- A0+A1 fused: renorm embedding rows -> M = row @ inW^T; last x-block runs A-structure check ----------
__global__ __launch_bounds__(256) void k_mbuild(
    const float* __restrict__ seqW, const float* __restrict__ tisW,
    const float* __restrict__ inW, const float* __restrict__ A_log,
    float* __restrict__ ws)
{
    int v = blockIdx.x, tid = threadIdx.x;
    if (v == VOCAB + N_TIS) {               // fused k_check (one block)
        if (blockIdx.y != 0) return;
        __shared__ int oksh;
        if (tid == 0) oksh = 1;
        __syncthreads();
        int ok = 1;
        for (int i = tid; i < D_INNER*D_STATE; i += 256) {
            int s = i & 15;
            float val = A_log[i];
            if (val != A_log[s]) ok = 0;                 // rows identical over d
            if (i < 16) {
                float a = __expf(val);                   // -A_s ~ (s+1)
                if (fabsf(a - (float)(s+1)) > 1e-3f*(float)(s+1)) ok = 0;
            }
        }
        if (!ok) atomicAnd(&oksh, 0);
        __syncthreads();
        if (tid == 0) ((int*)ws)[OFF_FLAG] = oksh;
        return;
    }

    __shared__ float a_l[256];
    __shared__ float red[4];
    int K, wofs; const float* src; float* dstM;
    if (v < VOCAB) { K = 256; wofs = 0;   src = seqW + (size_t)v*256;        dstM = ws + OFF_MSEQ + (size_t)v*1280; }
    else           { K = 64;  wofs = 256; src = tisW + (size_t)(v-VOCAB)*64; dstM = ws + OFF_MTIS + (size_t)(v-VOCAB)*1280; }
    float x = (tid < K) ? src[tid] : 0.0f;
    float ss = x * x;
    #pragma unroll
    for (int o = 32; o; o >>= 1) ss += __shfl_xor(ss, o);
    if ((tid & 63) == 0) red[tid >> 6] = ss;
    __syncthreads();
    float tot = red[0] + red[1] + red[2] + red[3];
    float scale = fminf(1.0f, 2.0f / fmaxf(sqrtf(tot), 1e-12f));
    a_l[tid] = (tid < K) ? x * scale : 0.0f;
    __syncthreads();

    int wv = tid >> 6, l = tid & 63;
    float4 a4 = ((const float4*)a_l)[l];
    int j0 = blockIdx.y * 256 + wv * 64;
    bool lane_on = (4*l < K);
    for (int jj = 0; jj < 64; jj += 4) {
        float p[4];
        #pragma unroll
        for (int u = 0; u < 4; ++u) {
            float pv = 0.0f;
            if (lane_on) {
                const float4 w4 = *(const float4*)(inW + (size_t)(j0 + jj + u)*320 + wofs + 4*l);
                pv = a4.x*w4.x + a4.y*w4.y + a4.z*w4.z + a4.w*w4.w;
            }
            p[u] = pv;
        }
        float ta, tb;
        ta=__shfl_xor(p[0],1); tb=__shfl_xor(p[1],1); p[0]=(l&1)?(p[1]+tb):(p[0]+ta);
        ta=__shfl_xor(p[2],1); tb=__shfl_xor(p[3],1); p[2]=(l&1)?(p[3]+tb):(p[2]+ta);
        ta=__shfl_xor(p[0],2); tb=__shfl_xor(p[2],2); p[0]=(l&2)?(p[2]+tb):(p[0]+ta);
        p[0]+=__shfl_xor(p[0],4);  p[0]+=__shfl_xor(p[0],8);
        p[0]+=__shfl_xor(p[0],16); p[0]+=__shfl_xor(p[0],32);
        if (l < 4) dstM[j0 + jj + l] = p[0];
    }
}

// ---------- K2: conv+silu -> x_proj rows 0..35 -> XDB[b][t][36]; C at t_last ----------
__global__ __launch_bounds__(256) void k_xdbl(
    const int* __restrict__ idx, const int* __restrict__ tissue_id,
    const int* __restrict__ seq_lengths,
    const float* __restrict__ conv_w, const float* __restrict__ conv_b,
    const float* __restrict__ xW, float* __restrict__ ws)
{
    __shared__ float u_l[TT*641];
    __shared__ float xd_l[TT*36];
    __shared__ int   idx_l[TT+3];
    int b = blockIdx.y;
    int t0 = blockIdx.x * TT;
    int t_last = seq_lengths[b] - 1;
    if (t0 > t_last) return;
    int tid = threadIdx.x;
    const float* Mseq = ws + OFF_MSEQ;
    const float* Mtis = ws + OFF_MTIS;
    int tis = tissue_id[b];
    if (tid < TT+3) {
        int t = t0 - 3 + tid;
        idx_l[tid] = (t >= 0) ? idx[b*L_ + t] : 0;
    }
    __syncthreads();

    for (int d = tid; d < D_INNER; d += 256) {
        float w0 = conv_w[d*4+0], w1 = conv_w[d*4+1], w2 = conv_w[d*4+2], w3 = conv_w[d*4+3];
        float cb = conv_b[d];
        float mt = Mtis[(size_t)tis*1280 + d];
        float xzv[TT+3];
        #pragma unroll
        for (int k = 0; k < TT+3; ++k) {
            unsigned ro = (unsigned)idx_l[k] * 1280u;
            xzv[k] = ro ? (Mseq[ro + (unsigned)d] + mt) : 0.0f;
        }
        #pragma unroll
        for (int t = 0; t < TT; ++t) {
            float c = cb;
            c = fmaf(w0, xzv[t+0], c);
            c = fmaf(w1, xzv[t+1], c);
            c = fmaf(w2, xzv[t+2], c);
            c = fmaf(w3, xzv[t+3], c);
            u_l[t*641 + d] = silu_f(c);
        }
    }
    __syncthreads();

    {
        int w = tid >> 6, l = tid & 63;
        float wreg[9][10];
        #pragma unroll
        for (int kk = 0; kk < 9; ++kk) {
            const float* xr = xW + (size_t)(w + 4*kk)*D_INNER + l;
            #pragma unroll
            for (int i = 0; i < 10; ++i) wreg[kk][i] = xr[64*i];
        }
        for (int t = 0; t < TT; ++t) {
            float p[9];
            #pragma unroll
            for (int kk = 0; kk < 9; ++kk) p[kk] = 0.f;
            #pragma unroll
            for (int i = 0; i < 10; ++i) {
                float ui = u_l[t*641 + l + 64*i];
                #pragma unroll
                for (int kk = 0; kk < 9; ++kk) p[kk] = fmaf(wreg[kk][i], ui, p[kk]);
            }
            // merge-tree reduce: 9 partial-registers -> 1 (lane l<9 holds output l)
            {
                float ta, tb;
                ta=__shfl_xor(p[0],1); tb=__shfl_xor(p[1],1); p[0]=(l&1)?(p[1]+tb):(p[0]+ta);
                ta=__shfl_xor(p[2],1); tb=__shfl_xor(p[3],1); p[2]=(l&1)?(p[3]+tb):(p[2]+ta);
                ta=__shfl_xor(p[4],1); tb=__shfl_xor(p[5],1); p[4]=(l&1)?(p[5]+tb):(p[4]+ta);
                ta=__shfl_xor(p[6],1); tb=__shfl_xor(p[7],1); p[6]=(l&1)?(p[7]+tb):(p[6]+ta);
                p[8]+=__shfl_xor(p[8],1);
                ta=__shfl_xor(p[0],2); tb=__shfl_xor(p[2],2); p[0]=(l&2)?(p[2]+tb):(p[0]+ta);
                ta=__shfl_xor(p[4],2); tb=__shfl_xor(p[6],2); p[4]=(l&2)?(p[6]+tb):(p[4]+ta);
                p[8]+=__shfl_xor(p[8],2);
                ta=__shfl_xor(p[0],4); tb=__shfl_xor(p[4],4); p[0]=(l&4)?(p[4]+tb):(p[0]+ta);
                p[8]+=__shfl_xor(p[8],4);
                ta=__shfl_xor(p[0],8); tb=__shfl_xor(p[8],8); p[0]=(l&8)?(p[8]+tb):(p[0]+ta);
                p[0]+=__shfl_xor(p[0],16);
                p[0]+=__shfl_xor(p[0],32);
            }
            if (l < 9) xd_l[t*36 + w + 4*l] = p[0];
        }
        if (t_last < t0 + TT) {
            int tl = t_last - t0;
            float pc[4];
            #pragma unroll
            for (int k = 0; k < 4; ++k) pc[k] = 0.f;
            #pragma unroll
            for (int i = 0; i < 10; ++i) {
                float ui = u_l[tl*641 + l + 64*i];
                #pragma unroll
                for (int k = 0; k < 4; ++k)
                    pc[k] = fmaf(xW[(size_t)(36 + w + 4*k)*D_INNER + l + 64*i], ui, pc[k]);
            }
            #pragma unroll
            for (int o = 32; o; o >>= 1) {
                #pragma unroll
                for (int k = 0; k < 4; ++k) pc[k] += __shfl_xor(pc[k], o);
            }
            if (l == 0) {
                #pragma unroll
                for (int k = 0; k < 4; ++k) ws[OFF_CLAST + b*16 + w + 4*k] = pc[k];
            }
        }
    }
    __syncthreads();

    // write-out: single contiguous copy of the [t][36] tile
    {
        int nt = min(TT, t_last - t0 + 1);
        int cnt = nt * 36;
        float* dst = ws + OFF_XDB + ((size_t)b*L_ + t0)*36;
        for (int o = tid; o < cnt; o += 256) dst[o] = xd_l[o];
    }
}

// ---------- K3n: power-form scan (A_s = -(s+1); flag-gated), fully prefetched ----------
// d-per-lane; backward t in 32-t chunk; 1 exp2 per (d,t). ALL 9 float4 (dt rows + B rows)
// + conv gather prefetched one full iteration ahead; COMPUTE is pure register ALU.
// F folded into the power tree: q_n = F*E^n (19 muls total vs 15+16).
__global__ __launch_bounds__(128) void k_scan2(
    const int* __restrict__ idx, const int* __restrict__ tissue_id,
    const int* __restrict__ seq_lengths,
    const float* __restrict__ conv_w, const float* __restrict__ conv_b,
    const float* __restrict__ dtW, const float* __restrict__ dtb,
    float* __restrict__ ws)
{
    if (((const int*)ws)[OFF_FLAG] == 0) return;
    int b = blockIdx.y, c = blockIdx.z;
    int t_last = seq_lengths[b] - 1;
    int t_begin = c * CHL2;
    if (t_begin > t_last) return;
    int t_end = min(t_begin + CHL2 - 1, t_last);
    int d = blockIdx.x * 128 + threadIdx.x;
    unsigned dof = (unsigned)d;
    int tis = tissue_id[b];
    const float* Mseq = ws + OFF_MSEQ;
    const float4* XB  = (const float4*)(ws + OFF_XDB) + (size_t)b*L_*9;  // 9 float4 per t
    const int* idxb = idx + b*L_;

    float dtw_r[20];
    #pragma unroll
    for (int i = 0; i < 20; i += 4) {
        float4 w4 = *(const float4*)(dtW + d*20 + i);
        dtw_r[i] = w4.x; dtw_r[i+1] = w4.y; dtw_r[i+2] = w4.z; dtw_r[i+3] = w4.w;
    }
    float4 cw4 = *(const float4*)(conv_w + d*4);
    float  cb  = conv_b[d];
    float  dtb_v = dtb[d];
    float  mt  = ws[OFF_MTIS + (size_t)tis*1280 + d];
    const float L2E = 1.44269504089f;

    auto gath = [&](int t) -> float {
        int row = (t >= 0) ? idxb[t] : 0;
        return row ? (Mseq[(unsigned)row*1280u + dof] + mt) : 0.0f;
    };

    // conv window for t_end: xw0 = x(t_end-3) ... xw3 = x(t_end)
    float xw3 = gath(t_end);
    float xw2 = gath(t_end-1);
    float xw1 = gath(t_end-2);
    float xw0 = gath(t_end-3);

    float h[16];
    #pragma unroll
    for (int s = 0; s < 16; ++s) h[s] = 0.f;
    float r = 0.f;

    float4 A0,A1,A2,A3,A4, AB0,AB1,AB2,AB3; float GA;
    float4 E0,E1,E2,E3,E4, EB0,EB1,EB2,EB3; float GE;

#define LOADT(P0,P1,P2,P3,P4,Q0,Q1,Q2,Q3,G,tt) { \
    const float4* _p = XB + (size_t)(tt)*9; \
    P0=_p[0]; P1=_p[1]; P2=_p[2]; P3=_p[3]; P4=_p[4]; \
    Q0=_p[5]; Q1=_p[6]; Q2=_p[7]; Q3=_p[8]; \
    G = gath((tt)-4); }

#define COMPUTE(P0,P1,P2,P3,P4,Q0,Q1,Q2,Q3,G) { \
    float cc = cb; \
    cc = fmaf(cw4.x, xw0, cc); cc = fmaf(cw4.y, xw1, cc); \
    cc = fmaf(cw4.z, xw2, cc); cc = fmaf(cw4.w, xw3, cc); \
    float uu = silu_f(cc); \
    float x = dtb_v; \
    x = fmaf(P0.x, dtw_r[0],  x); x = fmaf(P0.y, dtw_r[1],  x); \
    x = fmaf(P0.z, dtw_r[2],  x); x = fmaf(P0.w, dtw_r[3],  x); \
    x = fmaf(P1.x, dtw_r[4],  x); x = fmaf(P1.y, dtw_r[5],  x); \
    x = fmaf(P1.z, dtw_r[6],  x); x = fmaf(P1.w, dtw_r[7],  x); \
    x = fmaf(P2.x, dtw_r[8],  x); x = fmaf(P2.y, dtw_r[9],  x); \
    x = fmaf(P2.z, dtw_r[10], x); x = fmaf(P2.w, dtw_r[11], x); \
    x = fmaf(P3.x, dtw_r[12], x); x = fmaf(P3.y, dtw_r[13], x); \
    x = fmaf(P3.z, dtw_r[14], x); x = fmaf(P3.w, dtw_r[15], x); \
    x = fmaf(P4.x, dtw_r[16], x); x = fmaf(P4.y, dtw_r[17], x); \
    x = fmaf(P4.z, dtw_r[18], x); x = fmaf(P4.w, dtw_r[19], x); \
    float ee = __expf(-fabsf(x)); \
    float dl = fmaxf(x, 0.0f) + __logf(1.0f + ee); \
    float F  = dl * uu; \
    float p1 = exp2f(-L2E * r); \
    float p2 = p1*p1, p4 = p2*p2, p8 = p4*p4; \
    float q1 = F*p1,  q2 = q1*p1, q3 = q1*p2, q4 = q2*p2; \
    float q5 = q1*p4, q6 = q2*p4, q7 = q3*p4, q8 = q4*p4; \
    float q9 = q1*p8, q10= q2*p8, q11= q3*p8, q12= q4*p8; \
    float q13= q5*p8, q14= q6*p8, q15= q7*p8, q16= q8*p8; \
    h[0]  = fmaf(Q0.x, q1,  h[0]);  h[1]  = fmaf(Q0.y, q2,  h[1]); \
    h[2]  = fmaf(Q0.z, q3,  h[2]);  h[3]  = fmaf(Q0.w, q4,  h[3]); \
    h[4]  = fmaf(Q1.x, q5,  h[4]);  h[5]  = fmaf(Q1.y, q6,  h[5]); \
    h[6]  = fmaf(Q1.z, q7,  h[6]);  h[7]  = fmaf(Q1.w, q8,  h[7]); \
    h[8]  = fmaf(Q2.x, q9,  h[8]);  h[9]  = fmaf(Q2.y, q10, h[9]); \
    h[10] = fmaf(Q2.z, q11, h[10]); h[11] = fmaf(Q2.w, q12, h[11]); \
    h[12] = fmaf(Q3.x, q13, h[12]); h[13] = fmaf(Q3.y, q14, h[13]); \
    h[14] = fmaf(Q3.z, q15, h[14]); h[15] = fmaf(Q3.w, q16, h[15]); \
    r += dl; \
    xw3 = xw2; xw2 = xw1; xw1 = xw0; xw0 = G; }

    int t = t_end;
    LOADT(A0,A1,A2,A3,A4,AB0,AB1,AB2,AB3,GA, t);
    for (;;) {
        int tb = t - 1;
        bool hasB = (tb >= t_begin);
        if (hasB) LOADT(E0,E1,E2,E3,E4,EB0,EB1,EB2,EB3,GE, tb);
        COMPUTE(A0,A1,A2,A3,A4,AB0,AB1,AB2,AB3,GA);
        if (!hasB) break;
        int ta = t - 2;
        bool hasA = (ta >= t_begin);
        if (hasA) LOADT(A0,A1,A2,A3,A4,AB0,AB1,AB2,AB3,GA, ta);
        COMPUTE(E0,E1,E2,E3,E4,EB0,EB1,EB2,EB3,GE);
        if (!hasA) break;
        t = ta;
    }
#undef LOADT
#undef COMPUTE

    // chunk transfer: Es (P_s = Es^(s+1) reconstructed in k_comb) + h[16]
    ws[OFF_PCN + ((size_t)b*NCH2 + c)*D_INNER + d] = exp2f(-L2E * r);
    float* dst = ws + OFF_SCN + (((size_t)b*NCH2 + c)*D_INNER + d)*16;
    ((float4*)dst)[0] = make_float4(h[0],  h[1],  h[2],  h[3]);
    ((float4*)dst)[1] = make_float4(h[4],  h[5],  h[6],  h[7]);
    ((float4*)dst)[2] = make_float4(h[8],  h[9],  h[10], h[11]);
    ((float4*)dst)[3] = make_float4(h[12], h[13], h[14], h[15]);
}

// ---------- K3: fallback chunk-parallel fused scan (general A; flag==0 only) ----------
__global__ __launch_bounds__(256) void k_scanc(
    const int* __restrict__ idx, const int* __restrict__ tissue_id,
    const int* __restrict__ seq_lengths,
    const float* __restrict__ conv_w, const float* __restrict__ conv_b,
    const float* __restrict__ dtW, const float* __restrict__ dtb,
    const float* __restrict__ A_log, float* __restrict__ ws)
{
    if (((const int*)ws)[OFF_FLAG] != 0) return;
    __shared__ float xd_t[ST*20];
    __shared__ float dl_t[16*68];
    __shared__ float du_t[16*68];
    __shared__ float Bb_t[16*68];
    __shared__ float sdred[16*17];
    __shared__ int   idx_t[ST+3];

    int dg = blockIdx.x, b = blockIdx.y, c = blockIdx.z;
    int t_last = seq_lengths[b] - 1;
    int t_begin = c * CHLEN;
    if (t_begin > t_last) return;
    int t_end = min(t_begin + CHLEN - 1, t_last);
    int tid = threadIdx.x;
    int dl = tid >> 4, s = tid & 15;
    int dd = tid & 15, tg = tid >> 4;
    int d_own = dg*16 + dd;
    unsigned dco = (unsigned)d_own;
    int tis = tissue_id[b];
    const float* Mseq = ws + OFF_MSEQ;

    float dtw_r[20];
    #pragma unroll
    for (int i = 0; i < 20; i += 4) {
        float4 w4 = *(const float4*)(dtW + d_own*20 + i);
        dtw_r[i] = w4.x; dtw_r[i+1] = w4.y; dtw_r[i+2] = w4.z; dtw_r[i+3] = w4.w;
    }
    float4 cw4 = *(const float4*)(conv_w + d_own*4);
    float  cb  = conv_b[d_own];
    float  dtb_v = dtb[d_own];
    float  mt  = ws[OFF_MTIS + (size_t)tis*1280 + d_own];
    float As = -__expf(A_log[(dg*16 + dl)*D_STATE + s]) * 1.44269504089f;

    float h = 0.0f;
    float sdp = 0.0f;
    for (int t0 = t_begin; t0 <= t_end; t0 += ST) {
        int nt = min(ST, t_end - t0 + 1);
        if (tid < ST+3) {
            int t = t0 - 3 + tid;
            idx_t[tid] = (t >= 0 && t < L_) ? idx[b*L_ + t] : 0;
        }
        {   // stage dt rows from XDB (stride 9 float4, take first 5)
            int cnt = nt * 5;
            for (int o = tid; o < cnt; o += 256) {
                int t = o / 5, q = o - t*5;
                ((float4*)xd_t)[o] =
                    *((const float4*)(ws + OFF_XDB) + ((size_t)b*L_ + t0 + t)*9 + q);
            }
        }
        {   // stage B rows transposed to [s][t]
            int cnt = nt * 16;
            for (int o = tid; o < cnt; o += 256) {
                int t = o >> 4, sB = o & 15;
                Bb_t[sB*68 + t] = ws[OFF_XDB + ((size_t)b*L_ + t0 + t)*36 + 20 + sB];
            }
        }
        __syncthreads();

        {
            int ttb = tg * 4;
            if (ttb < nt) {
                float xz[7];
                #pragma unroll
                for (int k = 0; k < 7; ++k) {
                    unsigned ro = (unsigned)idx_t[ttb + k] * 1280u;
                    xz[k] = ro ? (Mseq[ro + dco] + mt) : 0.0f;
                }
                float dl4[4], du4[4];
                bool full = (ttb + 3 < nt);
                #pragma unroll
                for (int j = 0; j < 4; ++j) {
                    int tt = ttb + j;
                    if (full || tt < nt) {
                        float cc = cb;
                        cc = fmaf(cw4.x, xz[j+0], cc);
                        cc = fmaf(cw4.y, xz[j+1], cc);
                        cc = fmaf(cw4.z, xz[j+2], cc);
                        cc = fmaf(cw4.w, xz[j+3], cc);
                        float u = silu_f(cc);
                        const float* xr = xd_t + tt*20;
                        float x = dtb_v;
                        #pragma unroll
                        for (int rr = 0; rr < 20; rr += 4) {
                            float4 x4 = *(const float4*)(xr + rr);
                            x = fmaf(x4.x, dtw_r[rr+0], x);
                            x = fmaf(x4.y, dtw_r[rr+1], x);
                            x = fmaf(x4.z, dtw_r[rr+2], x);
                            x = fmaf(x4.w, dtw_r[rr+3], x);
                        }
                        float e = __expf(-fabsf(x));
                        float sp = fmaxf(x, 0.0f) + __logf(1.0f + e);
                        dl4[j] = sp;
                        du4[j] = sp * u;
                        sdp += sp;
                    } else { dl4[j] = 0.f; du4[j] = 0.f; }
                }
                if (full) {
                    *(float4*)(dl_t + dd*68 + ttb) = make_float4(dl4[0], dl4[1], dl4[2], dl4[3]);
                    *(float4*)(du_t + dd*68 + ttb) = make_float4(du4[0], du4[1], du4[2], du4[3]);
                } else {
                    for (int j = 0; j < 4 && ttb + j < nt; ++j) {
                        dl_t[dd*68 + ttb + j] = dl4[j];
                        du_t[dd*68 + ttb + j] = du4[j];
                    }
                }
            }
        }
        __syncthreads();

        {
            int q4 = nt >> 2;
            #pragma unroll 8
            for (int q = 0; q < q4; ++q) {
                float4 d4 = *(const float4*)(dl_t + dl*68 + 4*q);
                float4 u4 = *(const float4*)(du_t + dl*68 + 4*q);
                float4 b4 = *(const float4*)(Bb_t + s*68 + 4*q);
                float e0 = exp2f(d4.x*As), e1 = exp2f(d4.y*As);
                float e2 = exp2f(d4.z*As), e3 = exp2f(d4.w*As);
                float c0 = u4.x*b4.x, c1 = u4.y*b4.y;
                float c2 = u4.z*b4.z, c3 = u4.w*b4.w;
                h = fmaf(e0, h, c0); h = fmaf(e1, h, c1);
                h = fmaf(e2, h, c2); h = fmaf(e3, h, c3);
            }
            for (int tt = q4*4; tt < nt; ++tt) {
                float dlt = dl_t[dl*68 + tt];
                h = fmaf(exp2f(dlt * As), h, du_t[dl*68 + tt] * Bb_t[s*68 + tt]);
            }
        }
        __syncthreads();
    }
    sdred[tg*17 + dd] = sdp;
    __syncthreads();
    float sd = 0.0f;
    #pragma unroll
    for (int g = 0; g < 16; ++g) sd += sdred[g*17 + dl];
    float P = exp2f(As * sd);
    size_t base = (((size_t)b*NCHUNK + c)*40 + dg)*256 + tid;
    ws[OFF_PC + base] = P;
    ws[OFF_SC + base] = h;
}

// ---------- K3b: combine chunk transfers (8-wide load batching), apply C_last, reduce over s ----------
__global__ __launch_bounds__(256) void k_comb(const int* __restrict__ seq_lengths,
                                              float* __restrict__ ws)
{
    int b = blockIdx.y, dg = blockIdx.x;
    int tid = threadIdx.x;
    int dl = tid >> 4, s = tid & 15;
    int t_last = seq_lengths[b] - 1;
    int flag = ((const int*)ws)[OFF_FLAG];
    float h = 0.0f;
    if (flag) {
        int d = dg*16 + dl;
        int n = s + 1;
        int ncv = t_last / CHL2 + 1;
        const float* Ep = ws + OFF_PCN + (size_t)b*NCH2*D_INNER + d;
        const float* Sp = ws + OFF_SCN + ((size_t)b*NCH2*D_INNER + d)*16 + s;
        for (int c0 = 0; c0 < ncv; c0 += 8) {
            float Ev[8], Sv[8];
            #pragma unroll
            for (int i = 0; i < 8; ++i) {
                bool valid = (c0 + i < ncv);
                Ev[i] = valid ? Ep[(size_t)(c0+i)*D_INNER] : 1.0f;
                Sv[i] = valid ? Sp[(size_t)(c0+i)*D_INNER*16] : 0.0f;
            }
            #pragma unroll
            for (int i = 0; i < 8; ++i) {
                float Es = Ev[i];
                float e2 = Es*Es, e4 = e2*e2, e8 = e4*e4, e16 = e8*e8;
                float W = (n & 1) ? Es : 1.0f;
                W *= (n & 2)  ? e2  : 1.0f;
                W *= (n & 4)  ? e4  : 1.0f;
                W *= (n & 8)  ? e8  : 1.0f;
                W *= (n & 16) ? e16 : 1.0f;
                h = fmaf(W, h, Sv[i]);
            }
        }
    } else {
        int ncv = t_last / CHLEN + 1;
        for (int c = 0; c < ncv; ++c) {
            size_t base = (((size_t)b*NCHUNK + c)*40 + dg)*256 + tid;
            h = fmaf(ws[OFF_PC + base], h, ws[OFF_SC + base]);
        }
    }
    float v = h * ws[OFF_CLAST + b*16 + s];
    v += __shfl_xor(v, 1); v += __shfl_xor(v, 2);
    v += __shfl_xor(v, 4); v += __shfl_xor(v, 8);
    if (s == 0) ws[OFF_YSCAN + (size_t)b*D_INNER + dg*16 + dl] = v;
}

// ---------- K5: per-batch epilogue, 1024 threads: parallel dots ----------
__global__ __launch_bounds__(1024) void k_final(
    const int* __restrict__ idx, const int* __restrict__ tissue_id,
    const int* __restrict__ seq_lengths,
    const float* __restrict__ conv_w, const float* __restrict__ conv_b,
    const float* __restrict__ Dskip, const float* __restrict__ outW,
    const float* __restrict__ p1W, const float* __restrict__ p1b,
    const float* __restrict__ p2W, const float* __restrict__ p2b,
    const float* __restrict__ ws, float* __restrict__ out)
{
    __shared__ float y_l[D_INNER];
    __shared__ float o_l[D_MODEL];
    __shared__ float h1_l[H_OUT];
    int b = blockIdx.x, tid = threadIdx.x;
    int t_last = seq_lengths[b] - 1;
    int tis = tissue_id[b];
    const float* Mseq = ws + OFF_MSEQ;
    const float* Mtis = ws + OFF_MTIS;
    int rows[4];
    #pragma unroll
    for (int k = 0; k < 4; ++k) {
        int t = t_last - 3 + k;
        rows[k] = (t >= 0) ? idx[b*L_ + t] : 0;
    }
    if (tid < D_INNER) {
        int d = tid;
        float conv = conv_b[d];
        const float* cw = conv_w + d*4;
        #pragma unroll
        for (int k = 0; k < 4; ++k) {
            unsigned ro = (unsigned)rows[k] * 1280u;
            float xzv = ro ? (Mseq[ro + (unsigned)d] + Mtis[(size_t)tis*1280 + d]) : 0.0f;
            conv += cw[k] * xzv;
        }
        float u = silu_f(conv);
        unsigned roL = (unsigned)rows[3] * 1280u;
        float z = roL ? (Mseq[roL + 640u + (unsigned)d] + Mtis[(size_t)tis*1280 + 640 + d]) : 0.0f;
        float ys = ws[OFF_YSCAN + (size_t)b*D_INNER + d];
        y_l[d] = (ys + u * Dskip[d]) * silu_f(z);
    }
    __syncthreads();
    {
        int j = tid >> 1, half = tid & 1;
        float acc = 0.f;
        if (j < D_MODEL) {
            const float* w = outW + (size_t)j*D_INNER + half*320;
            const float* y = y_l + half*320;
            #pragma unroll 4
            for (int k = 0; k < 320; k += 4) {
                float4 w4 = *(const float4*)(w + k);
                acc += y[k]*w4.x + y[k+1]*w4.y + y[k+2]*w4.z + y[k+3]*w4.w;
            }
        }
        acc += __shfl_xor(acc, 1);
        if (j < D_MODEL && half == 0) o_l[j] = acc;
    }
    __syncthreads();
    {
        int j = tid >> 3, part = tid & 7;
        float acc = 0.f;
        if (j < H_OUT) {
            const float* w = p1W + (size_t)j*D_MODEL + part*40;
            const float* o = o_l + part*40;
            #pragma unroll
            for (int k = 0; k < 40; k += 4) {
                float4 w4 = *(const float4*)(w + k);
                acc += o[k]*w4.x + o[k+1]*w4.y + o[k+2]*w4.z + o[k+3]*w4.w;
            }
        }
        acc += __shfl_xor(acc, 1); acc += __shfl_xor(acc, 2); acc += __shfl_xor(acc, 4);
        if (j < H_OUT && part == 0) h1_l[j] = fmaxf(acc + p1b[j], 0.0f);
    }
    __syncthreads();
    if (tid < 64) {
        float v = h1_l[tid]*p2W[tid] + h1_l[tid+64]*p2W[tid+64];
        v += __shfl_xor(v, 32); v += __shfl_xor(v, 16); v += __shfl_xor(v, 8);
        v += __shfl_xor(v, 4);  v += __shfl_xor(v, 2);  v += __shfl_xor(v, 1);
        if (tid == 0) out[b] = v + p2b[0];
    }
}

extern "C" void kernel_launch(void* const* d_in, const int* in_sizes, int n_in,
                              void* d_out, int out_size, void* d_ws, size_t ws_size,
                              hipStream_t stream)
{
    const int*   idx   = (const int*)d_in[0];
    const int*   tis   = (const int*)d_in[1];
    const int*   slen  = (const int*)d_in[2];
    const float* seqW  = (const float*)d_in[3];
    const float* tisW  = (const float*)d_in[4];
    const float* inW   = (const float*)d_in[5];
    const float* convw = (const float*)d_in[6];
    const float* convb = (const float*)d_in[7];
    const float* xW    = (const float*)d_in[8];
    const float* dtW   = (const float*)d_in[9];
    const float* dtb   = (const float*)d_in[10];
    const float* Alog  = (const float*)d_in[11];
    const float* Dsk   = (const float*)d_in[12];
    const float* outW  = (const float*)d_in[13];
    const float* p1W   = (const float*)d_in[14];
    const float* p1b   = (const float*)d_in[15];
    const float* p2W   = (const float*)d_in[16];
    const float* p2b   = (const float*)d_in[17];
    float* ws  = (float*)d_ws;
    float* out = (float*)d_out;

    hipLaunchKernelGGL(k_mbuild, dim3(VOCAB + N_TIS + 1, 5), dim3(256), 0, stream,
                       seqW, tisW, inW, Alog, ws);
    hipLaunchKernelGGL(k_xdbl,   dim3(L_/TT, B_),        dim3(256), 0, stream,
                       idx, tis, slen, convw, convb, xW, ws);
    hipLaunchKernelGGL(k_scan2,  dim3(D_INNER/128, B_, NCH2), dim3(128), 0, stream,
                       idx, tis, slen, convw, convb, dtW, dtb, ws);
    hipLaunchKernelGGL(k_scanc,  dim3(D_INNER/16, B_, NCHUNK), dim3(256), 0, stream,
                       idx, tis, slen, convw, convb, dtW, dtb, Alog, ws);
    hipLaunchKernelGGL(k_comb,   dim3(D_INNER/16, B_),   dim3(256), 0, stream, slen, ws);
    hipLaunchKernelGGL(k_final,  dim3(B_),               dim3(1024), 0, stream,
                       idx, tis, slen, convw, convb, Dsk, outW, p1W, p1b, p2W, p2b, ws, out);
}